// Round 11
// baseline (429.309 us; speedup 1.0000x reference)
//
#include <hip/hip_runtime.h>
#include <hip/hip_bf16.h>
#include <math.h>
#include <stdint.h>

typedef __hip_bfloat16 bf16;
typedef __hip_bfloat162 bf162;
typedef __attribute__((ext_vector_type(8))) short short8;
typedef __attribute__((ext_vector_type(4))) float f32x4;
#define HEADS 5

static inline long long cdivll(long long a, long long b){ return (a + b - 1) / b; }

__device__ __forceinline__ float b2f(bf16 v){ return __bfloat162float(v); }
__device__ __forceinline__ bf16 f2b(float v){ return __float2bfloat16(v); }
__device__ __forceinline__ short f2bs(float x){ bf16 b = __float2bfloat16(x); return *reinterpret_cast<short*>(&b); }
__device__ __forceinline__ float ldp(const void* p, long long i, int f32){
  return f32 ? ((const float*)p)[i] : b2f(((const bf16*)p)[i]);
}
__device__ __forceinline__ int eidx(const int* ei, long long i, int i64){
  return i64 ? ei[2 * i] : ei[i];
}
__device__ __forceinline__ float lrelu(float x, float a){ return x >= 0.f ? x : a * x; }
__device__ __forceinline__ float splus(float x){ return fmaxf(x, 0.f) + log1pf(expf(-fabsf(x))); }

// ---------------- runtime dtype detection ----------------
__global__ void k_detect(const unsigned short* xh, const int* ei, int* flags){
  __shared__ int r0[256], r1[256];
  int t = threadIdx.x;
  int nan_cnt = 0;
  for (int i = t; i < 8192; i += 256){
    unsigned short u = xh[i];
    if (((u >> 7) & 0xFF) == 0xFF) nan_cnt++;
  }
  int odd_nz = 0;
  for (int i = 1 + 2 * t; i < 1024; i += 512) if (ei[i] != 0) odd_nz++;
  r0[t] = nan_cnt; r1[t] = odd_nz; __syncthreads();
  for (int o = 128; o > 0; o >>= 1){
    if (t < o){ r0[t] += r0[t + o]; r1[t] += r1[t + o]; }
    __syncthreads();
  }
  if (t == 0){
    flags[0] = (r0[0] > 0) ? 1 : 0;
    flags[1] = (r1[0] == 0) ? 1 : 0;
  }
}

__global__ void k_stampfill(bf16* out, long long n, float code){
  long long i = (long long)blockIdx.x * blockDim.x + threadIdx.x;
  if (i < n) out[i] = f2b(i == 0 ? code : 0.f);
}

// ---------------- CSR build ----------------
__global__ void k_hist(const int* ei, int E, int N, int* counts, const int* flags){
  int i64 = flags[1];
  int e = blockIdx.x * blockDim.x + threadIdx.x;
  if (e >= E + N) return;
  int d = (e < E) ? eidx(ei, (long long)E + e, i64) : (e - E);
  atomicAdd(&counts[d], 1);
}
__global__ __launch_bounds__(1024) void k_scan(const int* counts, int* rowptr, int N){
  __shared__ int sums[1024];
  int t = threadIdx.x;
  int chunk = (N + 1023) / 1024;
  int start = t * chunk;
  int end = start + chunk; if (end > N) end = N;
  int s = 0;
  for (int i = start; i < end; ++i) s += counts[i];
  sums[t] = s; __syncthreads();
  for (int o = 1; o < 1024; o <<= 1){
    int v = (t >= o) ? sums[t - o] : 0;
    __syncthreads();
    sums[t] += v;
    __syncthreads();
  }
  int run = (t == 0) ? 0 : sums[t - 1];
  for (int i = start; i < end; ++i){ rowptr[i] = run; run += counts[i]; }
  if (t == 0) rowptr[N] = sums[1023];
}
__global__ void k_scatter(const int* ei, int E, int N, const int* rowptr, int* cursor,
                          unsigned short* colu, const int* flags){
  int i64 = flags[1];
  int e = blockIdx.x * blockDim.x + threadIdx.x;
  if (e >= E + N) return;
  int s, d;
  if (e < E){ s = eidx(ei, e, i64); d = eidx(ei, (long long)E + e, i64); }
  else { s = d = e - E; }
  int pos = rowptr[d] + atomicAdd(&cursor[d], 1);
  colu[pos] = (unsigned short)s;
}
__global__ void k_dinv(const int* rowptr, float* dinv, int N){
  int i = blockIdx.x * blockDim.x + threadIdx.x;
  if (i < N) dinv[i] = rsqrtf((float)(rowptr[i + 1] - rowptr[i]));
}

// ------------- pack ALL weights -> WT arena [c][k]; also zeroes CNT/CUR -------------
// hk != 0: GAT head-fold pack: out[c][h*K + k] = W[k][h*C + c]  (Kp = hk*K, Cp = C)
struct PackDesc { const void* W; int K, Kp, C, Cp, off, hk; };
struct PackArgs { PackDesc d[10]; int total; };
__global__ void k_packall(PackArgs P, bf16* WTA, int* cnt, int ncnt, const int* flags){
  int f32 = flags[0];
  int idx = blockIdx.x * blockDim.x + threadIdx.x;
  if (idx >= P.total){
    int z = idx - P.total;
    if (z < ncnt) cnt[z] = 0;
    return;
  }
  int base = 0;
#pragma unroll
  for (int s = 0; s < 10; ++s){
    int sz = P.d[s].Kp * P.d[s].Cp;
    if (idx < base + sz){
      int local = idx - base;
      int c = local / P.d[s].Kp;
      int k = local - c * P.d[s].Kp;
      float v;
      if (P.d[s].hk){
        int h = k / P.d[s].K;
        int kk = k - h * P.d[s].K;
        v = (c < P.d[s].C)
          ? ldp(P.d[s].W, (long long)kk * (P.d[s].hk * P.d[s].C) + h * P.d[s].C + c, f32) : 0.f;
      } else {
        v = (k < P.d[s].K && c < P.d[s].C)
          ? ldp(P.d[s].W, (long long)k * P.d[s].C + c, f32) : 0.f;
      }
      WTA[P.d[s].off + local] = f2b(v);
      return;
    }
    base += sz;
  }
}

// ------------- fold attention vectors into small dot weights -------------
__global__ void k_att_fold(const void* w1, const void* as1, const void* ad1,
                           const void* w2, const void* as2, const void* ad2,
                           bf16* wta, const int* flags){
  int f32 = flags[0];
  int idx = blockIdx.x * blockDim.x + threadIdx.x;
  if (idx < 8192){
    int c = idx >> 7, k = idx & 127;
    float v = 0.f;
    if (c < 10){
      int h = (c < 5) ? c : c - 5;
      const void* aw = (c < 5) ? as1 : ad1;
      for (int j = 0; j < 128; ++j)
        v = fmaf(ldp(w1, (long long)k * 640 + h * 128 + j, f32), ldp(aw, h * 128 + j, f32), v);
    }
    wta[186368 + idx] = f2b(v);
  } else if (idx < 12288){
    int l = idx - 8192;
    int c = l >> 6, k = l & 63;
    float v = 0.f;
    if (c < 10){
      int h = (c < 5) ? c : c - 5;
      const void* aw = (c < 5) ? as2 : ad2;
      for (int j = 0; j < 64; ++j)
        v = fmaf(ldp(w2, (long long)k * 320 + h * 64 + j, f32), ldp(aw, h * 64 + j, f32), v);
    }
    wta[194560 + l] = f2b(v);
  }
}

// ------------- fused nn1 MLP, 16 rows/block, col-split across 4 waves:
//   x_in[N,64] -> softplus -> [N,128] -> softplus -> [N,64] -> bn0+leaky -> X[N,128] f32
//   AND gcn1 projection -> HX[N,128] bf16.  Weights: WTA @ 0 / 8192 / 16384 / 24576.
__global__ __launch_bounds__(256) void k_nn1f(
    const void* xin, const bf16* WTA,
    const void* b1, const void* b2, const void* b3,
    const void* g0, const void* bb0, const void* m0, const void* v0,
    float* X, bf16* hx, int N, const int* flags)
{
  __shared__ bf16 s1[16][136];
  __shared__ bf16 s2[16][72];
  int f32 = flags[0];
  int t = threadIdx.x, wave = t >> 6, lane = t & 63;
  int quad = lane >> 4, l15 = lane & 15;
  int mbase = blockIdx.x * 16;
  int m = mbase + l15; if (m > N - 1) m = N - 1;

  // ---- stage 1: K=64 -> C=128 (wave w: j = 2w, 2w+1) ----
  f32x4 a1[2];
#pragma unroll
  for (int j = 0; j < 2; ++j) a1[j] = (f32x4){0.f, 0.f, 0.f, 0.f};
#pragma unroll
  for (int k0 = 0; k0 < 64; k0 += 32){
    int ka = k0 + quad * 8;
    short8 af;
    if (!f32){
      af = *(const short8*)((const bf16*)xin + (size_t)m * 64 + ka);
    } else {
      const float* p = (const float*)xin + (size_t)m * 64 + ka;
      float4 v0v = *(const float4*)p;
      float4 v1v = *(const float4*)(p + 4);
      af[0] = f2bs(v0v.x); af[1] = f2bs(v0v.y); af[2] = f2bs(v0v.z); af[3] = f2bs(v0v.w);
      af[4] = f2bs(v1v.x); af[5] = f2bs(v1v.y); af[6] = f2bs(v1v.z); af[7] = f2bs(v1v.w);
    }
#pragma unroll
    for (int jj = 0; jj < 2; ++jj){
      int j = wave * 2 + jj;
      short8 bvv = *(const short8*)(WTA + (size_t)(16 * j + l15) * 64 + ka);
      a1[jj] = __builtin_amdgcn_mfma_f32_16x16x32_bf16(af, bvv, a1[jj], 0, 0, 0);
    }
  }
#pragma unroll
  for (int jj = 0; jj < 2; ++jj){
    int c = 16 * (wave * 2 + jj) + l15;
    float bi = ldp(b1, c, f32);
#pragma unroll
    for (int r = 0; r < 4; ++r)
      s1[quad * 4 + r][c] = f2b(splus(a1[jj][r] + bi));
  }
  __syncthreads();

  // ---- stage 2: K=128 -> C=64 (wave w: j = w) ----
  f32x4 a2 = (f32x4){0.f, 0.f, 0.f, 0.f};
#pragma unroll
  for (int k0 = 0; k0 < 128; k0 += 32){
    int ka = k0 + quad * 8;
    short8 af = *(const short8*)&s1[l15][ka];
    short8 bvv = *(const short8*)(WTA + 8192 + (size_t)(16 * wave + l15) * 128 + ka);
    a2 = __builtin_amdgcn_mfma_f32_16x16x32_bf16(af, bvv, a2, 0, 0, 0);
  }
  {
    int c = 16 * wave + l15;
    float bi = ldp(b2, c, f32);
#pragma unroll
    for (int r = 0; r < 4; ++r)
      s2[quad * 4 + r][c] = f2b(splus(a2[r] + bi));
  }
  __syncthreads();

  // ---- stage 3: K=64 -> C=128, bn0+leaky -> X f32 + s1 (dead buffer) ----
  f32x4 a3[2];
#pragma unroll
  for (int j = 0; j < 2; ++j) a3[j] = (f32x4){0.f, 0.f, 0.f, 0.f};
#pragma unroll
  for (int k0 = 0; k0 < 64; k0 += 32){
    int ka = k0 + quad * 8;
    short8 af = *(const short8*)&s2[l15][ka];
#pragma unroll
    for (int jj = 0; jj < 2; ++jj){
      int j = wave * 2 + jj;
      short8 bvv = *(const short8*)(WTA + 16384 + (size_t)(16 * j + l15) * 64 + ka);
      a3[jj] = __builtin_amdgcn_mfma_f32_16x16x32_bf16(af, bvv, a3[jj], 0, 0, 0);
    }
  }
#pragma unroll
  for (int jj = 0; jj < 2; ++jj){
    int c = 16 * (wave * 2 + jj) + l15;
    float bi = ldp(b3, c, f32);
    float g = ldp(g0, c, f32), be = ldp(bb0, c, f32), mm = ldp(m0, c, f32);
    float iv = rsqrtf(ldp(v0, c, f32) + 1e-5f);
#pragma unroll
    for (int r = 0; r < 4; ++r){
      int n = mbase + quad * 4 + r;
      float y = a3[jj][r] + bi;
      y = (y - mm) * iv * g + be;
      y = lrelu(y, 0.01f);
      if (n < N) X[(size_t)n * 128 + c] = y;
      s1[quad * 4 + r][c] = f2b(y);
    }
  }
  __syncthreads();

  // ---- stage 4: gcn1 projection K=128 -> C=128 -> HX bf16 ----
  f32x4 a4[2];
#pragma unroll
  for (int j = 0; j < 2; ++j) a4[j] = (f32x4){0.f, 0.f, 0.f, 0.f};
#pragma unroll
  for (int k0 = 0; k0 < 128; k0 += 32){
    int ka = k0 + quad * 8;
    short8 af = *(const short8*)&s1[l15][ka];
#pragma unroll
    for (int jj = 0; jj < 2; ++jj){
      int j = wave * 2 + jj;
      short8 bvv = *(const short8*)(WTA + 24576 + (size_t)(16 * j + l15) * 128 + ka);
      a4[jj] = __builtin_amdgcn_mfma_f32_16x16x32_bf16(af, bvv, a4[jj], 0, 0, 0);
    }
  }
#pragma unroll
  for (int jj = 0; jj < 2; ++jj){
    int c = 16 * (wave * 2 + jj) + l15;
#pragma unroll
    for (int r = 0; r < 4; ++r){
      int n = mbase + quad * 4 + r;
      if (n < N) hx[(size_t)n * 128 + c] = f2b(a4[jj][r]);
    }
  }
}

// ------------- fused node_pred MLP, 16 rows/block, col-split across 4 waves:
//   d_out[N,192] -> 96 -> 48 -> 24 -> dot24+sigmoid -> d_out[N*192 + n].
__global__ __launch_bounds__(256) void k_mlpf(
    const void* dout, const bf16* WTA,
    const void* b1, const void* b2, const void* b3,
    const void* w4, const void* b4, void* outfin, int N, const int* flags)
{
  __shared__ bf16 s1[16][104];
  __shared__ bf16 s2[16][72];
  __shared__ float part[2][16];
  int f32 = flags[0];
  int t = threadIdx.x, wave = t >> 6, lane = t & 63;
  int quad = lane >> 4, l15 = lane & 15;
  int mbase = blockIdx.x * 16;
  int m = mbase + l15; if (m > N - 1) m = N - 1;

  // ---- stage 1: K=192 -> C=96 (wave w: j = w and w+4 if <6) ----
  f32x4 a1[2];
#pragma unroll
  for (int j = 0; j < 2; ++j) a1[j] = (f32x4){0.f, 0.f, 0.f, 0.f};
#pragma unroll
  for (int k0 = 0; k0 < 192; k0 += 32){
    int ka = k0 + quad * 8;
    short8 af;
    if (!f32){
      af = *(const short8*)((const bf16*)dout + (size_t)m * 192 + ka);
    } else {
      const float* p = (const float*)dout + (size_t)m * 192 + ka;
      float4 v0 = *(const float4*)p;
      float4 v1 = *(const float4*)(p + 4);
      af[0] = f2bs(v0.x); af[1] = f2bs(v0.y); af[2] = f2bs(v0.z); af[3] = f2bs(v0.w);
      af[4] = f2bs(v1.x); af[5] = f2bs(v1.y); af[6] = f2bs(v1.z); af[7] = f2bs(v1.w);
    }
#pragma unroll
    for (int jj = 0; jj < 2; ++jj){
      int j = wave + 4 * jj;
      if (j < 6){
        short8 bvv = *(const short8*)(WTA + 151552 + (size_t)(16 * j + l15) * 192 + ka);
        a1[jj] = __builtin_amdgcn_mfma_f32_16x16x32_bf16(af, bvv, a1[jj], 0, 0, 0);
      }
    }
  }
#pragma unroll
  for (int jj = 0; jj < 2; ++jj){
    int j = wave + 4 * jj;
    if (j < 6){
      int c = 16 * j + l15;
      float bi = ldp(b1, c, f32);
#pragma unroll
      for (int r = 0; r < 4; ++r)
        s1[quad * 4 + r][c] = f2b(splus(a1[jj][r] + bi));
    }
  }
  __syncthreads();

  // ---- stage 2: K=96 -> C=48 (waves 0..2: j=w; wave 3: zero-fill cols 48..63) ----
  if (wave < 3){
    f32x4 a2 = (f32x4){0.f, 0.f, 0.f, 0.f};
#pragma unroll
    for (int k0 = 0; k0 < 96; k0 += 32){
      int ka = k0 + quad * 8;
      short8 af = *(const short8*)&s1[l15][ka];
      short8 bvv = *(const short8*)(WTA + 176128 + (size_t)(16 * wave + l15) * 96 + ka);
      a2 = __builtin_amdgcn_mfma_f32_16x16x32_bf16(af, bvv, a2, 0, 0, 0);
    }
    int c = 16 * wave + l15;
    float bi = ldp(b2, c, f32);
#pragma unroll
    for (int r = 0; r < 4; ++r)
      s2[quad * 4 + r][c] = f2b(splus(a2[r] + bi));
  } else {
#pragma unroll
    for (int r = 0; r < 4; ++r)
      s2[quad * 4 + r][48 + l15] = f2b(0.f);
  }
  __syncthreads();

  // ---- stage 3: K=64 -> C=32 (waves 0,1: j=w) + dot24 partials ----
  if (wave < 2){
    f32x4 a3 = (f32x4){0.f, 0.f, 0.f, 0.f};
#pragma unroll
    for (int k0 = 0; k0 < 64; k0 += 32){
      int ka = k0 + quad * 8;
      short8 af = *(const short8*)&s2[l15][ka];
      short8 bvv = *(const short8*)(WTA + 182272 + (size_t)(16 * wave + l15) * 64 + ka);
      a3 = __builtin_amdgcn_mfma_f32_16x16x32_bf16(af, bvv, a3, 0, 0, 0);
    }
    int c = 16 * wave + l15;
    float w = (c < 24) ? ldp(w4, c, f32) : 0.f;
    float bi = (c < 24) ? ldp(b3, c, f32) : 0.f;
    float pr[4];
#pragma unroll
    for (int r = 0; r < 4; ++r){
      pr[r] = splus(a3[r] + bi) * w;
#pragma unroll
      for (int o = 1; o < 16; o <<= 1) pr[r] += __shfl_xor(pr[r], o);
      if (l15 == 0) part[wave][quad * 4 + r] = pr[r];
    }
  }
  __syncthreads();
  if (t < 16){
    int n = mbase + t;
    if (n < N){
      float p = 1.f / (1.f + expf(-(part[0][t] + part[1][t] + ldp(b4, 0, f32))));
      long long oi = (long long)N * 192 + n;
      if (f32) ((float*)outfin)[oi] = p; else ((bf16*)outfin)[oi] = f2b(p);
    }
  }
}

// ------------- GCN aggregate via CSR (h bf16) -> BB bf16, + fused att-logit dots -------------
__global__ __launch_bounds__(256) void k_gcn_csr(
    const int* rowptr, const unsigned short* colu, const bf16* h,
    const float* dinv, const void* bias, bf16* outb, int N, int C,
    const bf16* watt, float* asd, const int* flags)
{
  int f32 = flags[0];
  int wid = (blockIdx.x * 256 + threadIdx.x) >> 6;
  int lane = threadIdx.x & 63;
  if (wid >= N) return;
  int i0 = rowptr[wid], i1 = rowptr[wid + 1];
  float dr = dinv[wid];
  if (C == 128){
    int coff = lane << 1;
    float ax[4] = {0.f, 0.f, 0.f, 0.f}, ay[4] = {0.f, 0.f, 0.f, 0.f};
    int i = i0;
    for (; i + 7 < i1; i += 8){
      int s[8];
#pragma unroll
      for (int e = 0; e < 8; ++e) s[e] = colu[i + e];
      bf162 v[8]; float f[8];
#pragma unroll
      for (int e = 0; e < 8; ++e){
        v[e] = *(const bf162*)(h + (size_t)s[e] * 128 + coff);
        f[e] = dinv[s[e]];
      }
#pragma unroll
      for (int e = 0; e < 8; ++e){
        ax[e & 3] = fmaf(f[e], b2f(v[e].x), ax[e & 3]);
        ay[e & 3] = fmaf(f[e], b2f(v[e].y), ay[e & 3]);
      }
    }
    for (; i + 3 < i1; i += 4){
      int s[4] = {colu[i], colu[i + 1], colu[i + 2], colu[i + 3]};
#pragma unroll
      for (int e = 0; e < 4; ++e){
        bf162 v = *(const bf162*)(h + (size_t)s[e] * 128 + coff);
        float f = dinv[s[e]];
        ax[e] = fmaf(f, b2f(v.x), ax[e]); ay[e] = fmaf(f, b2f(v.y), ay[e]);
      }
    }
    for (; i < i1; ++i){
      int s0 = colu[i];
      bf162 v = *(const bf162*)(h + (size_t)s0 * 128 + coff);
      float f = dinv[s0];
      ax[0] = fmaf(f, b2f(v.x), ax[0]); ay[0] = fmaf(f, b2f(v.y), ay[0]);
    }
    float sx = (ax[0] + ax[1]) + (ax[2] + ax[3]);
    float sy = (ay[0] + ay[1]) + (ay[2] + ay[3]);
    float vx = sx * dr + ldp(bias, coff, f32);
    float vy = sy * dr + ldp(bias, coff + 1, f32);
    bf162 o; o.x = f2b(vx); o.y = f2b(vy);
    *(bf162*)(outb + (size_t)wid * 128 + coff) = o;
    if (watt){
      float myv = 0.f;
#pragma unroll
      for (int hh = 0; hh < 10; ++hh){
        bf162 w = *(const bf162*)(watt + hh * 128 + coff);
        float p = vx * b2f(w.x) + vy * b2f(w.y);
#pragma unroll
        for (int o2 = 1; o2 < 64; o2 <<= 1) p += __shfl_xor(p, o2);
        if (lane == hh) myv = p;
      }
      if (lane < 10) asd[(size_t)wid * 10 + lane] = myv;
    }
  } else { // C == 64: half-waves, up to 4 edges per half in flight
    int half = lane >> 5, hl = lane & 31;
    int coff = hl << 1;
    float ax = 0.f, ay = 0.f, bx = 0.f, by = 0.f;
    int i = i0;
    for (; i + 7 < i1; i += 8){
      int sA = colu[i + half],     sB = colu[i + 2 + half];
      int sC = colu[i + 4 + half], sD = colu[i + 6 + half];
      bf162 vA = *(const bf162*)(h + (size_t)sA * 64 + coff);
      bf162 vB = *(const bf162*)(h + (size_t)sB * 64 + coff);
      bf162 vC = *(const bf162*)(h + (size_t)sC * 64 + coff);
      bf162 vD = *(const bf162*)(h + (size_t)sD * 64 + coff);
      float fA = dinv[sA], fB = dinv[sB], fC = dinv[sC], fD = dinv[sD];
      ax = fmaf(fA, b2f(vA.x), ax); ay = fmaf(fA, b2f(vA.y), ay);
      bx = fmaf(fB, b2f(vB.x), bx); by = fmaf(fB, b2f(vB.y), by);
      ax = fmaf(fC, b2f(vC.x), ax); ay = fmaf(fC, b2f(vC.y), ay);
      bx = fmaf(fD, b2f(vD.x), bx); by = fmaf(fD, b2f(vD.y), by);
    }
    for (; i + 3 < i1; i += 4){
      int sA = colu[i + half], sB = colu[i + 2 + half];
      bf162 vA = *(const bf162*)(h + (size_t)sA * 64 + coff);
      bf162 vB = *(const bf162*)(h + (size_t)sB * 64 + coff);
      float fA = dinv[sA], fB = dinv[sB];
      ax = fmaf(fA, b2f(vA.x), ax); ay = fmaf(fA, b2f(vA.y), ay);
      bx = fmaf(fB, b2f(vB.x), bx); by = fmaf(fB, b2f(vB.y), by);
    }
    for (; i + 1 < i1; i += 2){
      int s = colu[i + half];
      bf162 v = *(const bf162*)(h + (size_t)s * 64 + coff);
      float f = dinv[s];
      ax = fmaf(f, b2f(v.x), ax); ay = fmaf(f, b2f(v.y), ay);
    }
    if (i < i1 && half == 0){
      int s = colu[i];
      bf162 v = *(const bf162*)(h + (size_t)s * 64 + coff);
      float f = dinv[s];
      ax = fmaf(f, b2f(v.x), ax); ay = fmaf(f, b2f(v.y), ay);
    }
    ax += bx; ay += by;
    ax += __shfl_xor(ax, 32);
    ay += __shfl_xor(ay, 32);
    float vx = ax * dr + ldp(bias, coff, f32);
    float vy = ay * dr + ldp(bias, coff + 1, f32);
    if (half == 0){
      bf162 o; o.x = f2b(vx); o.y = f2b(vy);
      *(bf162*)(outb + (size_t)wid * 64 + coff) = o;
    }
    if (watt){
      float myv = 0.f;
#pragma unroll
      for (int hh = 0; hh < 10; ++hh){
        bf162 w = *(const bf162*)(watt + hh * 64 + coff);
        float p = vx * b2f(w.x) + vy * b2f(w.y);
#pragma unroll
        for (int o2 = 1; o2 < 32; o2 <<= 1) p += __shfl_xor(p, o2);
        if (lane == hh) myv = p;
      }
      if (lane < 10) asd[(size_t)wid * 10 + lane] = myv;
    }
  }
}

// ------------- FUSED GAT: single-pass unnormalized softmax + alpha-gather (into LDS)
//               + MFMA projection + bias + BN + leaky (+skip) -> d_out;
//               optional gcn2 projection -> hx.
// Block: 8 waves (512 thr), 8 rows, one row per wave (finer blocks -> 4 blocks/CU,
// full 32-wave occupancy, less straggler imbalance). MFMA uses M=16 with rows 8..15
// discarded (independent M-rows; stores guarded to row<8).
template<int K>
__global__ __launch_bounds__(512) void k_gat_proj(
    const int* rowptr, const unsigned short* colu, const bf16* bbx,
    const float* asd, const bf16* WT, const void* bias,
    const void* bg, const void* bbp, const void* bm, const void* bv,
    const float* skip, void* dout, int c2off,
    const bf16* WT2, bf16* hx, int N, const int* flags)
{
  constexpr int KP  = HEADS * K;              // 640 / 320
  constexpr int AGP = (K == 128) ? 648 : 328; // row pad: bank offset 4 -> 2-way only
  constexpr int C   = K;
  constexpr int NCG = C / 16;                 // col groups (8 / 4)
  constexpr int NW  = 8;                      // waves = rows per block
  constexpr int KSPLIT = NW / NCG;            // 1 (K=128) / 2 (K=64)
  constexpr int KSEG = KP / KSPLIT;           // 640 / 160
  __shared__ bf16 agg[16][AGP];               // 16 rows for MFMA M; only 8 filled
  __shared__ float als[NW][HEADS][64];
  __shared__ unsigned short ssrc[NW][64];
  int f32 = flags[0];
  int t = threadIdx.x, wave = t >> 6, lane = t & 63;
  int quad = lane >> 4, l15 = lane & 15;
  int rb = blockIdx.x * NW;

  // ---- phase 1: single-pass softmax + gather — wave handles row rb+wave ----
  int wid = rb + wave;
  if (wid < N){
    int i0 = rowptr[wid], i1 = rowptr[wid + 1];
    float adr[HEADS];
#pragma unroll
    for (int h = 0; h < HEADS; ++h) adr[h] = asd[(size_t)wid * 10 + 5 + h];
    float denl[HEADS];
#pragma unroll
    for (int h = 0; h < HEADS; ++h) denl[h] = 0.f;

    if constexpr (K == 128){
      int coff = lane << 1;
      float ax[HEADS], ay[HEADS];
#pragma unroll
      for (int h = 0; h < HEADS; ++h){ ax[h] = 0.f; ay[h] = 0.f; }
      for (int base = i0; base < i1; base += 64){
        int iend = i1 - base; if (iend > 64) iend = 64;
        int i = base + lane;
        if (i < i1){
          int s = colu[i];
          float2 q0 = *(const float2*)(asd + (size_t)s * 10);
          float2 q1 = *(const float2*)(asd + (size_t)s * 10 + 2);
          float q4 = asd[(size_t)s * 10 + 4];
          float w0 = expf(fminf(lrelu(q0.x + adr[0], 0.2f), 80.f));
          float w1 = expf(fminf(lrelu(q0.y + adr[1], 0.2f), 80.f));
          float w2 = expf(fminf(lrelu(q1.x + adr[2], 0.2f), 80.f));
          float w3 = expf(fminf(lrelu(q1.y + adr[3], 0.2f), 80.f));
          float w4 = expf(fminf(lrelu(q4 + adr[4], 0.2f), 80.f));
          ssrc[wave][lane] = (unsigned short)s;
          als[wave][0][lane] = w0; als[wave][1][lane] = w1;
          als[wave][2][lane] = w2; als[wave][3][lane] = w3;
          als[wave][4][lane] = w4;
          denl[0] += w0; denl[1] += w1; denl[2] += w2; denl[3] += w3; denl[4] += w4;
        }
        asm volatile("s_waitcnt lgkmcnt(0)" ::: "memory");
        int j = 0;
        for (; j + 7 < iend; j += 8){
          int s8[8];
#pragma unroll
          for (int e = 0; e < 8; ++e) s8[e] = ssrc[wave][j + e];
          bf162 v[8];
#pragma unroll
          for (int e = 0; e < 8; ++e) v[e] = *(const bf162*)(bbx + (size_t)s8[e] * 128 + coff);
#pragma unroll
          for (int e = 0; e < 8; ++e){
            float fx = b2f(v[e].x), fy = b2f(v[e].y);
#pragma unroll
            for (int h = 0; h < HEADS; ++h){
              float a = als[wave][h][j + e];
              ax[h] = fmaf(a, fx, ax[h]); ay[h] = fmaf(a, fy, ay[h]);
            }
          }
        }
        for (; j + 3 < iend; j += 4){
          int s4[4];
#pragma unroll
          for (int e = 0; e < 4; ++e) s4[e] = ssrc[wave][j + e];
          bf162 v[4];
#pragma unroll
          for (int e = 0; e < 4; ++e) v[e] = *(const bf162*)(bbx + (size_t)s4[e] * 128 + coff);
#pragma unroll
          for (int e = 0; e < 4; ++e){
            float fx = b2f(v[e].x), fy = b2f(v[e].y);
#pragma unroll
            for (int h = 0; h < HEADS; ++h){
              float a = als[wave][h][j + e];
              ax[h] = fmaf(a, fx, ax[h]); ay[h] = fmaf(a, fy, ay[h]);
            }
          }
        }
        for (; j < iend; ++j){
          int s = ssrc[wave][j];
          bf162 v = *(const bf162*)(bbx + (size_t)s * 128 + coff);
          float fx = b2f(v.x), fy = b2f(v.y);
#pragma unroll
          for (int h = 0; h < HEADS; ++h){
            float a = als[wave][h][j];
            ax[h] = fmaf(a, fx, ax[h]); ay[h] = fmaf(a, fy, ay[h]);
          }
        }
      }
      float dnv[HEADS];
#pragma unroll
      for (int h = 0; h < HEADS; ++h){
        float d = denl[h];
        for (int o = 32; o > 0; o >>= 1) d += __shfl_xor(d, o);
        dnv[h] = 1.f / (d * (float)HEADS);
      }
#pragma unroll
      for (int h = 0; h < HEADS; ++h){
        bf162 o; o.x = f2b(ax[h] * dnv[h]); o.y = f2b(ay[h] * dnv[h]);
        *(bf162*)&agg[wave][h * 128 + coff] = o;
      }
    } else { // K == 64: half-waves for gather; softmax on all 64 lanes
      int half = lane >> 5, hl = lane & 31;
      int coff = hl << 1;
      float ax[HEADS], ay[HEADS];
#pragma unroll
      for (int h = 0; h < HEADS; ++h){ ax[h] = 0.f; ay[h] = 0.f; }
      for (int base = i0; base < i1; base += 64){
        int iend = i1 - base; if (iend > 64) iend = 64;
        int i = base + lane;
        if (i < i1){
          int s = colu[i];
          float2 q0 = *(const float2*)(asd + (size_t)s * 10);
          float2 q1 = *(const float2*)(asd + (size_t)s * 10 + 2);
          float q4 = asd[(size_t)s * 10 + 4];
          float w0 = expf(fminf(lrelu(q0.x + adr[0], 0.2f), 80.f));
          float w1 = expf(fminf(lrelu(q0.y + adr[1], 0.2f), 80.f));
          float w2 = expf(fminf(lrelu(q1.x + adr[2], 0.2f), 80.f));
          float w3 = expf(fminf(lrelu(q1.y + adr[3], 0.2f), 80.f));
          float w4 = expf(fminf(lrelu(q4 + adr[4], 0.2f), 80.f));
          ssrc[wave][lane] = (unsigned short)s;
          als[wave][0][lane] = w0; als[wave][1][lane] = w1;
          als[wave][2][lane] = w2; als[wave][3][lane] = w3;
          als[wave][4][lane] = w4;
          denl[0] += w0; denl[1] += w1; denl[2] += w2; denl[3] += w3; denl[4] += w4;
        }
        asm volatile("s_waitcnt lgkmcnt(0)" ::: "memory");
        int j = 0;
        for (; j + 7 < iend; j += 8){
          int sA = ssrc[wave][j + half],     sB = ssrc[wave][j + 2 + half];
          int sC = ssrc[wave][j + 4 + half], sD = ssrc[wave][j + 6 + half];
          bf162 vA = *(const bf162*)(bbx + (size_t)sA * 64 + coff);
          bf162 vB = *(const bf162*)(bbx + (size_t)sB * 64 + coff);
          bf162 vC = *(const bf162*)(bbx + (size_t)sC * 64 + coff);
          bf162 vD = *(const bf162*)(bbx + (size_t)sD * 64 + coff);
          float Ax = b2f(vA.x), Ay = b2f(vA.y), Bx = b2f(vB.x), By = b2f(vB.y);
          float Cx = b2f(vC.x), Cy = b2f(vC.y), Dx = b2f(vD.x), Dy = b2f(vD.y);
#pragma unroll
          for (int h = 0; h < HEADS; ++h){
            float aA = als[wave][h][j + half],     aB = als[wave][h][j + 2 + half];
            float aC = als[wave][h][j + 4 + half], aD = als[wave][h][j + 6 + half];
            ax[h] = fmaf(aA, Ax, ax[h]); ay[h] = fmaf(aA, Ay, ay[h]);
            ax[h] = fmaf(aB, Bx, ax[h]); ay[h] = fmaf(aB, By, ay[h]);
            ax[h] = fmaf(aC, Cx, ax[h]); ay[h] = fmaf(aC, Cy, ay[h]);
            ax[h] = fmaf(aD, Dx, ax[h]); ay[h] = fmaf(aD, Dy, ay[h]);
          }
        }
        for (; j + 3 < iend; j += 4){
          int sA = ssrc[wave][j + half], sB = ssrc[wave][j + 2 + half];
          bf162 vA = *(const bf162*)(bbx + (size_t)sA * 64 + coff);
          bf162 vB = *(const bf162*)(bbx + (size_t)sB * 64 + coff);
          float Ax = b2f(vA.x), Ay = b2f(vA.y), Bx = b2f(vB.x), By = b2f(vB.y);
#pragma unroll
          for (int h = 0; h < HEADS; ++h){
            float aA = als[wave][h][j + half], aB = als[wave][h][j + 2 + half];
            ax[h] = fmaf(aA, Ax, ax[h]); ay[h] = fmaf(aA, Ay, ay[h]);
            ax[h] = fmaf(aB, Bx, ax[h]); ay[h] = fmaf(aB, By, ay[h]);
          }
        }
        for (; j + 1 < iend; j += 2){
          int s = ssrc[wave][j + half];
          bf162 v = *(const bf162*)(bbx + (size_t)s * 64 + coff);
          float fx = b2f(v.x), fy = b2f(v.y);
#pragma unroll
          for (int h = 0; h < HEADS; ++h){
            float a = als[wave][h][j + half];
            ax[h] = fmaf(a, fx, ax[h]); ay[h] = fmaf(a, fy, ay[h]);
          }
        }
        if (j < iend && half == 0){
          int s = ssrc[wave][j];
          bf162 v = *(const bf162*)(bbx + (size_t)s * 64 + coff);
          float fx = b2f(v.x), fy = b2f(v.y);
#pragma unroll
          for (int h = 0; h < HEADS; ++h){
            float a = als[wave][h][j];
            ax[h] = fmaf(a, fx, ax[h]); ay[h] = fmaf(a, fy, ay[h]);
          }
        }
      }
      float dnv[HEADS];
#pragma unroll
      for (int h = 0; h < HEADS; ++h){
        float d = denl[h];
        for (int o = 32; o > 0; o >>= 1) d += __shfl_xor(d, o);
        dnv[h] = 1.f / (d * (float)HEADS);
      }
#pragma unroll
      for (int h = 0; h < HEADS; ++h){
        ax[h] += __shfl_xor(ax[h], 32);
        ay[h] += __shfl_xor(ay[h], 32);
      }
      if (half == 0){
#pragma unroll
        for (int h = 0; h < HEADS; ++h){
          bf162 o; o.x = f2b(ax[h] * dnv[h]); o.y = f2b(ay[h] * dnv[h]);
          *(bf162*)&agg[wave][h * 64 + coff] = o;
        }
      }
    }
  }
  __syncthreads();

  // ---- phase 2: MFMA projection from LDS agg (M=16, rows 8..15 discarded) ----
  int cg = wave & (NCG - 1);
  int kh = wave / NCG;                 // 0..KSPLIT-1
  f32x4 acc = (f32x4){0.f, 0.f, 0.f, 0.f};
#pragma unroll
  for (int ks = 0; ks < KSEG; ks += 32){
    int ka = kh * KSEG + ks + quad * 8;
    short8 af = *(const short8*)&agg[l15][ka];
    short8 bvv = *(const short8*)(WT + (size_t)(cg * 16 + l15) * KP + ka);
    acc = __builtin_amdgcn_mfma_f32_16x16x32_bf16(af, bvv, acc, 0, 0, 0);
  }
  if constexpr (KSPLIT > 1){
    auto red = reinterpret_cast<float(*)[16][20]>(&als[0][0][0]);
    if (kh == 1){
#pragma unroll
      for (int r = 0; r < 4; ++r)
        red[cg][quad * 4 + r][l15] = acc[r];
    }
    __syncthreads();
    if (kh == 0){
#pragma unroll
      for (int r = 0; r < 4; ++r)
        acc[r] += red[cg][quad * 4 + r][l15];
    }
  }
  if (kh == 0){
    int c = cg * 16 + l15;
    float bi = ldp(bias, c, f32);
    float g = ldp(bg, c, f32), be = ldp(bbp, c, f32), mm = ldp(bm, c, f32);
    float iv = rsqrtf(ldp(bv, c, f32) + 1e-5f);
#pragma unroll
    for (int r = 0; r < 4; ++r){
      int row = quad * 4 + r;
      if (row >= NW) continue;
      int n = rb + row;
      if (n >= N) continue;
      float y = acc[r] + bi;
      y = (y - mm) * iv * g + be;
      y = lrelu(y, 0.01f);
      if (skip) y += skip[(size_t)n * 128 + c];
      size_t o = (size_t)n * 192 + c2off + c;
      if (f32) ((float*)dout)[o] = y; else ((bf16*)dout)[o] = f2b(y);
      if (WT2) agg[row][c] = f2b(y);   // skip1 tile for gcn2 projection
    }
  }

  // ---- stage 3 (gat1 only): project skip1 tile @ gcn2_w -> hx [N,64] bf16 ----
  if constexpr (K == 128){
    if (WT2){
      __syncthreads();
      int cg2 = wave & 3, kh2 = wave >> 2;   // split-K=2 over 128
      f32x4 a2 = (f32x4){0.f, 0.f, 0.f, 0.f};
#pragma unroll
      for (int ks = 0; ks < 2; ++ks){
        int ka = kh2 * 64 + ks * 32 + quad * 8;
        short8 af = *(const short8*)&agg[l15][ka];
        short8 bvv = *(const short8*)(WT2 + (size_t)(cg2 * 16 + l15) * 128 + ka);
        a2 = __builtin_amdgcn_mfma_f32_16x16x32_bf16(af, bvv, a2, 0, 0, 0);
      }
      auto red2 = reinterpret_cast<float(*)[16][20]>(&als[0][0][0]);
      if (kh2 == 1){
#pragma unroll
        for (int r = 0; r < 4; ++r)
          red2[cg2][quad * 4 + r][l15] = a2[r];
      }
      __syncthreads();
      if (kh2 == 0){
#pragma unroll
        for (int r = 0; r < 4; ++r)
          a2[r] += red2[cg2][quad * 4 + r][l15];
        int c2 = cg2 * 16 + l15;
#pragma unroll
        for (int r = 0; r < 4; ++r){
          int row = quad * 4 + r;
          if (row >= NW) continue;
          int n = rb + row;
          if (n < N) hx[(size_t)n * 64 + c2] = f2b(a2[r]);
        }
      }
    }
  }
}

extern "C" void kernel_launch(void* const* d_in, const int* in_sizes, int n_in,
                              void* d_out, int out_size, void* d_ws, size_t ws_size,
                              hipStream_t stream)
{
  const void* x_in   = d_in[0];
  const int*  ei     = (const int*)d_in[1];
  const void *nn1_w1 = d_in[2], *nn1_b1 = d_in[3], *nn1_w2 = d_in[4], *nn1_b2 = d_in[5];
  const void *nn1_w3 = d_in[6], *nn1_b3 = d_in[7];
  const void *bn0_g = d_in[8],  *bn0_b = d_in[9],  *bn0_m = d_in[10], *bn0_v = d_in[11];
  const void *bn1_g = d_in[12], *bn1_b = d_in[13], *bn1_m = d_in[14], *bn1_v = d_in[15];
  const void *bn2_g = d_in[16], *bn2_b = d_in[17], *bn2_m = d_in[18], *bn2_v = d_in[19];
  const void *gcn1_w = d_in[20], *gcn1_b = d_in[21];
  const void *gat1_w = d_in[22], *gat1_as = d_in[23], *gat1_ad = d_in[24], *gat1_b = d_in[25];
  const void *gcn2_w = d_in[26], *gcn2_b = d_in[27];
  const void *gat2_w = d_in[28], *gat2_as = d_in[29], *gat2_ad = d_in[30], *gat2_b = d_in[31];
  const void *mlp_w1 = d_in[32], *mlp_b1 = d_in[33], *mlp_w2 = d_in[34], *mlp_b2 = d_in[35];
  const void *mlp_w3 = d_in[36], *mlp_b3 = d_in[37], *mlp_w4 = d_in[38], *mlp_b4 = d_in[39];
  (void)n_in;

  const int N  = in_sizes[0] / 64;
  const int E  = in_sizes[1] / 2;
  const int Ep = E + N;
  const int TB = 256;

  if ((long long)out_size != (long long)N * 193 || N > 65535){
    k_stampfill<<<(int)cdivll(out_size, TB), TB, 0, stream>>>((bf16*)d_out, out_size, 8192.f);
    return;
  }
  size_t need = 2900ull * (size_t)N + 500000ull;
  if (ws_size < need){
    k_stampfill<<<(int)cdivll(out_size, TB), TB, 0, stream>>>((bf16*)d_out, out_size, 1024.f);
    return;
  }

  // ws layout: flags | X | A | B | DINV | ASD | rowptr | colu(u16) | HX(bf16) | WTA(bf16)
  char* wsb = (char*)d_ws;
  int*   FLAGS = (int*)wsb;
  float* X    = (float*)(wsb + 16);
  float* A    = X + (size_t)N * 128;
  float* B    = A + (size_t)N * 128;
  float* DINV = B + (size_t)N * 128;
  float* AS   = DINV + N;                       // [N][10] f32: a_src(5) | a_dst(5)
  int*   ROWP = (int*)(AS + (size_t)N * 2 * HEADS);
  unsigned short* COLU = (unsigned short*)(ROWP + N + 1);
  bf16*  HX   = (bf16*)(COLU + ((Ep + 7) & ~7)); // gcn projections [N,128]/[N,64] bf16
  bf16*  WTA  = (bf16*)(((uintptr_t)(HX + (size_t)N * 640) + 15) & ~(uintptr_t)15);
  bf16*  BB   = (bf16*)A;    // bf16 GCN output (gat input), aliases A
  int* CNT = (int*)AS;
  int* CUR = CNT + N;
  const int ATT1_OFF = 186368;   // [64][128] folded att weights (gat1)
  const int ATT2_OFF = 194560;   // [64][64]  folded att weights (gat2)

  k_detect<<<1, 256, 0, stream>>>((const unsigned short*)x_in, ei, FLAGS);

  // ---- pack all weights + zero CNT/CUR ----
  PackArgs P;
  P.d[0] = {nn1_w1,  64, 64, 128, 128, 0, 0};
  P.d[1] = {nn1_w2, 128,128,  64,  64, 8192, 0};
  P.d[2] = {nn1_w3,  64, 64, 128, 128, 16384, 0};
  P.d[3] = {gcn1_w, 128,128, 128, 128, 24576, 0};
  P.d[4] = {gat1_w, 128,640, 128, 128, 40960, 5};   // head-folded: [c][h*128+k]
  P.d[5] = {gcn2_w, 128,128,  64,  64, 122880, 0};
  P.d[6] = {gat2_w,  64,320,  64,  64, 131072, 5};  // head-folded: [c][h*64+k]
  P.d[7] = {mlp_w1, 192,192,  96, 128, 151552, 0};
  P.d[8] = {mlp_w2,  96, 96,  48,  64, 176128, 0};
  P.d[9] = {mlp_w3,  48, 64,  24,  64, 182272, 0};
  P.total = 186368;
  k_packall<<<(int)cdivll(P.total + 2 * N, TB), TB, 0, stream>>>(P, WTA, CNT, 2 * N, FLAGS);
  k_att_fold<<<48, 256, 0, stream>>>(gat1_w, gat1_as, gat1_ad, gat2_w, gat2_as, gat2_ad, WTA, FLAGS);

  // ---- CSR build ----
  k_hist<<<(int)cdivll(Ep, TB), TB, 0, stream>>>(ei, E, N, CNT, FLAGS);
  k_scan<<<1, 1024, 0, stream>>>(CNT, ROWP, N);
  k_scatter<<<(int)cdivll(Ep, TB), TB, 0, stream>>>(ei, E, N, ROWP, CUR, COLU, FLAGS);
  k_dinv<<<(int)cdivll(N, TB), TB, 0, stream>>>(ROWP, DINV, N);

  int rowsg = (int)cdivll(N, 4);
  int rows8 = (int)cdivll(N, 8);
  int rows16 = (int)cdivll(N, 16);

  // ---- stage A: fused nn1 MLP (+bn0+leaky) -> X f32, + gcn1 projection -> HX ----
  k_nn1f<<<rows16, 256, 0, stream>>>(x_in, WTA, nn1_b1, nn1_b2, nn1_b3,
                                     bn0_g, bn0_b, bn0_m, bn0_v, X, HX, N, FLAGS);

  // ---- GCN1 aggregate (+att1 logit dots) ----
  k_gcn_csr<<<rowsg, 256, 0, stream>>>(ROWP, COLU, HX, DINV, gcn1_b, BB, N, 128,
                                       WTA + ATT1_OFF, AS, FLAGS);

  // ---- GAT1: softmax+gather+project+bn1+skip -> d_out[:,0:128], + gcn2 proj -> HX[N,64]
  k_gat_proj<128><<<rows8, 512, 0, stream>>>(ROWP, COLU, BB, AS, WTA + 40960, gat1_b,
      bn1_g, bn1_b, bn1_m, bn1_v, X, d_out, 0, WTA + 122880, HX, N, FLAGS);

  // ---- GCN2 aggregate (+att2 dots) ----
  k_gcn_csr<<<rowsg, 256, 0, stream>>>(ROWP, COLU, HX, DINV, gcn2_b, BB, N, 64,
                                       WTA + ATT2_OFF, AS, FLAGS);

  // ---- GAT2: softmax+gather+project+bn2 -> d_out[:,128:192] ----
  k_gat_proj<64><<<rows8, 512, 0, stream>>>(ROWP, COLU, BB, AS, WTA + 131072, gat2_b,
      bn2_g, bn2_b, bn2_m, bn2_v, nullptr, d_out, 128, nullptr, nullptr, N, FLAGS);

  // ---- fused node_pred MLP: d_out[N,192] -> probs at d_out[N*192..] ----
  k_mlpf<<<rows16, 256, 0, stream>>>(d_out, WTA, mlp_b1, mlp_b2, mlp_b3,
                                     mlp_w4, mlp_b4, d_out, N, FLAGS);
}

// Round 12
// 412.548 us; speedup vs baseline: 1.0406x; 1.0406x over previous
//
#include <hip/hip_runtime.h>
#include <hip/hip_bf16.h>
#include <math.h>
#include <stdint.h>

typedef __hip_bfloat16 bf16;
typedef __hip_bfloat162 bf162;
typedef __attribute__((ext_vector_type(8))) short short8;
typedef __attribute__((ext_vector_type(4))) float f32x4;
#define HEADS 5

static inline long long cdivll(long long a, long long b){ return (a + b - 1) / b; }

__device__ __forceinline__ float b2f(bf16 v){ return __bfloat162float(v); }
__device__ __forceinline__ bf16 f2b(float v){ return __float2bfloat16(v); }
__device__ __forceinline__ short f2bs(float x){ bf16 b = __float2bfloat16(x); return *reinterpret_cast<short*>(&b); }
__device__ __forceinline__ float ldp(const void* p, long long i, int f32){
  return f32 ? ((const float*)p)[i] : b2f(((const bf16*)p)[i]);
}
__device__ __forceinline__ int eidx(const int* ei, long long i, int i64){
  return i64 ? ei[2 * i] : ei[i];
}
__device__ __forceinline__ float lrelu(float x, float a){ return x >= 0.f ? x : a * x; }
__device__ __forceinline__ float splus(float x){ return fmaxf(x, 0.f) + log1pf(expf(-fabsf(x))); }

// ---------------- runtime dtype detection ----------------
__global__ void k_detect(const unsigned short* xh, const int* ei, int* flags){
  __shared__ int r0[256], r1[256];
  int t = threadIdx.x;
  int nan_cnt = 0;
  for (int i = t; i < 8192; i += 256){
    unsigned short u = xh[i];
    if (((u >> 7) & 0xFF) == 0xFF) nan_cnt++;
  }
  int odd_nz = 0;
  for (int i = 1 + 2 * t; i < 1024; i += 512) if (ei[i] != 0) odd_nz++;
  r0[t] = nan_cnt; r1[t] = odd_nz; __syncthreads();
  for (int o = 128; o > 0; o >>= 1){
    if (t < o){ r0[t] += r0[t + o]; r1[t] += r1[t + o]; }
    __syncthreads();
  }
  if (t == 0){
    flags[0] = (r0[0] > 0) ? 1 : 0;
    flags[1] = (r1[0] == 0) ? 1 : 0;
  }
}

__global__ void k_stampfill(bf16* out, long long n, float code){
  long long i = (long long)blockIdx.x * blockDim.x + threadIdx.x;
  if (i < n) out[i] = f2b(i == 0 ? code : 0.f);
}

// ---------------- CSR build ----------------
__global__ void k_hist(const int* ei, int E, int N, int* counts, const int* flags){
  int i64 = flags[1];
  int e = blockIdx.x * blockDim.x + threadIdx.x;
  if (e >= E + N) return;
  int d = (e < E) ? eidx(ei, (long long)E + e, i64) : (e - E);
  atomicAdd(&counts[d], 1);
}
__global__ __launch_bounds__(1024) void k_scan(const int* counts, int* rowptr, int N){
  __shared__ int sums[1024];
  int t = threadIdx.x;
  int chunk = (N + 1023) / 1024;
  int start = t * chunk;
  int end = start + chunk; if (end > N) end = N;
  int s = 0;
  for (int i = start; i < end; ++i) s += counts[i];
  sums[t] = s; __syncthreads();
  for (int o = 1; o < 1024; o <<= 1){
    int v = (t >= o) ? sums[t - o] : 0;
    __syncthreads();
    sums[t] += v;
    __syncthreads();
  }
  int run = (t == 0) ? 0 : sums[t - 1];
  for (int i = start; i < end; ++i){ rowptr[i] = run; run += counts[i]; }
  if (t == 0) rowptr[N] = sums[1023];
}
__global__ void k_scatter(const int* ei, int E, int N, const int* rowptr, int* cursor,
                          unsigned short* colu, const int* flags){
  int i64 = flags[1];
  int e = blockIdx.x * blockDim.x + threadIdx.x;
  if (e >= E + N) return;
  int s, d;
  if (e < E){ s = eidx(ei, e, i64); d = eidx(ei, (long long)E + e, i64); }
  else { s = d = e - E; }
  int pos = rowptr[d] + atomicAdd(&cursor[d], 1);
  colu[pos] = (unsigned short)s;
}
__global__ void k_dinv(const int* rowptr, float* dinv, int N){
  int i = blockIdx.x * blockDim.x + threadIdx.x;
  if (i < N) dinv[i] = rsqrtf((float)(rowptr[i + 1] - rowptr[i]));
}

// ------------- pack ALL weights -> WT arena [c][k]; also zeroes CNT/CUR -------------
// hk != 0: GAT head-fold pack: out[c][h*K + k] = W[k][h*C + c]  (Kp = hk*K, Cp = C)
struct PackDesc { const void* W; int K, Kp, C, Cp, off, hk; };
struct PackArgs { PackDesc d[10]; int total; };
__global__ void k_packall(PackArgs P, bf16* WTA, int* cnt, int ncnt, const int* flags){
  int f32 = flags[0];
  int idx = blockIdx.x * blockDim.x + threadIdx.x;
  if (idx >= P.total){
    int z = idx - P.total;
    if (z < ncnt) cnt[z] = 0;
    return;
  }
  int base = 0;
#pragma unroll
  for (int s = 0; s < 10; ++s){
    int sz = P.d[s].Kp * P.d[s].Cp;
    if (idx < base + sz){
      int local = idx - base;
      int c = local / P.d[s].Kp;
      int k = local - c * P.d[s].Kp;
      float v;
      if (P.d[s].hk){
        int h = k / P.d[s].K;
        int kk = k - h * P.d[s].K;
        v = (c < P.d[s].C)
          ? ldp(P.d[s].W, (long long)kk * (P.d[s].hk * P.d[s].C) + h * P.d[s].C + c, f32) : 0.f;
      } else {
        v = (k < P.d[s].K && c < P.d[s].C)
          ? ldp(P.d[s].W, (long long)k * P.d[s].C + c, f32) : 0.f;
      }
      WTA[P.d[s].off + local] = f2b(v);
      return;
    }
    base += sz;
  }
}

// ------------- fold attention vectors into small dot weights -------------
__global__ void k_att_fold(const void* w1, const void* as1, const void* ad1,
                           const void* w2, const void* as2, const void* ad2,
                           bf16* wta, const int* flags){
  int f32 = flags[0];
  int idx = blockIdx.x * blockDim.x + threadIdx.x;
  if (idx < 8192){
    int c = idx >> 7, k = idx & 127;
    float v = 0.f;
    if (c < 10){
      int h = (c < 5) ? c : c - 5;
      const void* aw = (c < 5) ? as1 : ad1;
      for (int j = 0; j < 128; ++j)
        v = fmaf(ldp(w1, (long long)k * 640 + h * 128 + j, f32), ldp(aw, h * 128 + j, f32), v);
    }
    wta[186368 + idx] = f2b(v);
  } else if (idx < 12288){
    int l = idx - 8192;
    int c = l >> 6, k = l & 63;
    float v = 0.f;
    if (c < 10){
      int h = (c < 5) ? c : c - 5;
      const void* aw = (c < 5) ? as2 : ad2;
      for (int j = 0; j < 64; ++j)
        v = fmaf(ldp(w2, (long long)k * 320 + h * 64 + j, f32), ldp(aw, h * 64 + j, f32), v);
    }
    wta[194560 + l] = f2b(v);
  }
}

// ------------- fused nn1 MLP, 16 rows/block, col-split across 4 waves:
//   x_in[N,64] -> softplus -> [N,128] -> softplus -> [N,64] -> bn0+leaky -> X[N,128] f32
//   AND gcn1 projection -> HX[N,128] bf16.  Weights: WTA @ 0 / 8192 / 16384 / 24576.
__global__ __launch_bounds__(256) void k_nn1f(
    const void* xin, const bf16* WTA,
    const void* b1, const void* b2, const void* b3,
    const void* g0, const void* bb0, const void* m0, const void* v0,
    float* X, bf16* hx, int N, const int* flags)
{
  __shared__ bf16 s1[16][136];
  __shared__ bf16 s2[16][72];
  int f32 = flags[0];
  int t = threadIdx.x, wave = t >> 6, lane = t & 63;
  int quad = lane >> 4, l15 = lane & 15;
  int mbase = blockIdx.x * 16;
  int m = mbase + l15; if (m > N - 1) m = N - 1;

  // ---- stage 1: K=64 -> C=128 (wave w: j = 2w, 2w+1) ----
  f32x4 a1[2];
#pragma unroll
  for (int j = 0; j < 2; ++j) a1[j] = (f32x4){0.f, 0.f, 0.f, 0.f};
#pragma unroll
  for (int k0 = 0; k0 < 64; k0 += 32){
    int ka = k0 + quad * 8;
    short8 af;
    if (!f32){
      af = *(const short8*)((const bf16*)xin + (size_t)m * 64 + ka);
    } else {
      const float* p = (const float*)xin + (size_t)m * 64 + ka;
      float4 v0v = *(const float4*)p;
      float4 v1v = *(const float4*)(p + 4);
      af[0] = f2bs(v0v.x); af[1] = f2bs(v0v.y); af[2] = f2bs(v0v.z); af[3] = f2bs(v0v.w);
      af[4] = f2bs(v1v.x); af[5] = f2bs(v1v.y); af[6] = f2bs(v1v.z); af[7] = f2bs(v1v.w);
    }
#pragma unroll
    for (int jj = 0; jj < 2; ++jj){
      int j = wave * 2 + jj;
      short8 bvv = *(const short8*)(WTA + (size_t)(16 * j + l15) * 64 + ka);
      a1[jj] = __builtin_amdgcn_mfma_f32_16x16x32_bf16(af, bvv, a1[jj], 0, 0, 0);
    }
  }
#pragma unroll
  for (int jj = 0; jj < 2; ++jj){
    int c = 16 * (wave * 2 + jj) + l15;
    float bi = ldp(b1, c, f32);
#pragma unroll
    for (int r = 0; r < 4; ++r)
      s1[quad * 4 + r][c] = f2b(splus(a1[jj][r] + bi));
  }
  __syncthreads();

  // ---- stage 2: K=128 -> C=64 (wave w: j = w) ----
  f32x4 a2 = (f32x4){0.f, 0.f, 0.f, 0.f};
#pragma unroll
  for (int k0 = 0; k0 < 128; k0 += 32){
    int ka = k0 + quad * 8;
    short8 af = *(const short8*)&s1[l15][ka];
    short8 bvv = *(const short8*)(WTA + 8192 + (size_t)(16 * wave + l15) * 128 + ka);
    a2 = __builtin_amdgcn_mfma_f32_16x16x32_bf16(af, bvv, a2, 0, 0, 0);
  }
  {
    int c = 16 * wave + l15;
    float bi = ldp(b2, c, f32);
#pragma unroll
    for (int r = 0; r < 4; ++r)
      s2[quad * 4 + r][c] = f2b(splus(a2[r] + bi));
  }
  __syncthreads();

  // ---- stage 3: K=64 -> C=128, bn0+leaky -> X f32 + s1 (dead buffer) ----
  f32x4 a3[2];
#pragma unroll
  for (int j = 0; j < 2; ++j) a3[j] = (f32x4){0.f, 0.f, 0.f, 0.f};
#pragma unroll
  for (int k0 = 0; k0 < 64; k0 += 32){
    int ka = k0 + quad * 8;
    short8 af = *(const short8*)&s2[l15][ka];
#pragma unroll
    for (int jj = 0; jj < 2; ++jj){
      int j = wave * 2 + jj;
      short8 bvv = *(const short8*)(WTA + 16384 + (size_t)(16 * j + l15) * 64 + ka);
      a3[jj] = __builtin_amdgcn_mfma_f32_16x16x32_bf16(af, bvv, a3[jj], 0, 0, 0);
    }
  }
#pragma unroll
  for (int jj = 0; jj < 2; ++jj){
    int c = 16 * (wave * 2 + jj) + l15;
    float bi = ldp(b3, c, f32);
    float g = ldp(g0, c, f32), be = ldp(bb0, c, f32), mm = ldp(m0, c, f32);
    float iv = rsqrtf(ldp(v0, c, f32) + 1e-5f);
#pragma unroll
    for (int r = 0; r < 4; ++r){
      int n = mbase + quad * 4 + r;
      float y = a3[jj][r] + bi;
      y = (y - mm) * iv * g + be;
      y = lrelu(y, 0.01f);
      if (n < N) X[(size_t)n * 128 + c] = y;
      s1[quad * 4 + r][c] = f2b(y);
    }
  }
  __syncthreads();

  // ---- stage 4: gcn1 projection K=128 -> C=128 -> HX bf16 ----
  f32x4 a4[2];
#pragma unroll
  for (int j = 0; j < 2; ++j) a4[j] = (f32x4){0.f, 0.f, 0.f, 0.f};
#pragma unroll
  for (int k0 = 0; k0 < 128; k0 += 32){
    int ka = k0 + quad * 8;
    short8 af = *(const short8*)&s1[l15][ka];
#pragma unroll
    for (int jj = 0; jj < 2; ++jj){
      int j = wave * 2 + jj;
      short8 bvv = *(const short8*)(WTA + 24576 + (size_t)(16 * j + l15) * 128 + ka);
      a4[jj] = __builtin_amdgcn_mfma_f32_16x16x32_bf16(af, bvv, a4[jj], 0, 0, 0);
    }
  }
#pragma unroll
  for (int jj = 0; jj < 2; ++jj){
    int c = 16 * (wave * 2 + jj) + l15;
#pragma unroll
    for (int r = 0; r < 4; ++r){
      int n = mbase + quad * 4 + r;
      if (n < N) hx[(size_t)n * 128 + c] = f2b(a4[jj][r]);
    }
  }
}

// ------------- fused node_pred MLP, 16 rows/block, col-split across 4 waves:
//   d_out[N,192] -> 96 -> 48 -> 24 -> dot24+sigmoid -> d_out[N*192 + n].
__global__ __launch_bounds__(256) void k_mlpf(
    const void* dout, const bf16* WTA,
    const void* b1, const void* b2, const void* b3,
    const void* w4, const void* b4, void* outfin, int N, const int* flags)
{
  __shared__ bf16 s1[16][104];
  __shared__ bf16 s2[16][72];
  __shared__ float part[2][16];
  int f32 = flags[0];
  int t = threadIdx.x, wave = t >> 6, lane = t & 63;
  int quad = lane >> 4, l15 = lane & 15;
  int mbase = blockIdx.x * 16;
  int m = mbase + l15; if (m > N - 1) m = N - 1;

  // ---- stage 1: K=192 -> C=96 (wave w: j = w and w+4 if <6) ----
  f32x4 a1[2];
#pragma unroll
  for (int j = 0; j < 2; ++j) a1[j] = (f32x4){0.f, 0.f, 0.f, 0.f};
#pragma unroll
  for (int k0 = 0; k0 < 192; k0 += 32){
    int ka = k0 + quad * 8;
    short8 af;
    if (!f32){
      af = *(const short8*)((const bf16*)dout + (size_t)m * 192 + ka);
    } else {
      const float* p = (const float*)dout + (size_t)m * 192 + ka;
      float4 v0 = *(const float4*)p;
      float4 v1 = *(const float4*)(p + 4);
      af[0] = f2bs(v0.x); af[1] = f2bs(v0.y); af[2] = f2bs(v0.z); af[3] = f2bs(v0.w);
      af[4] = f2bs(v1.x); af[5] = f2bs(v1.y); af[6] = f2bs(v1.z); af[7] = f2bs(v1.w);
    }
#pragma unroll
    for (int jj = 0; jj < 2; ++jj){
      int j = wave + 4 * jj;
      if (j < 6){
        short8 bvv = *(const short8*)(WTA + 151552 + (size_t)(16 * j + l15) * 192 + ka);
        a1[jj] = __builtin_amdgcn_mfma_f32_16x16x32_bf16(af, bvv, a1[jj], 0, 0, 0);
      }
    }
  }
#pragma unroll
  for (int jj = 0; jj < 2; ++jj){
    int j = wave + 4 * jj;
    if (j < 6){
      int c = 16 * j + l15;
      float bi = ldp(b1, c, f32);
#pragma unroll
      for (int r = 0; r < 4; ++r)
        s1[quad * 4 + r][c] = f2b(splus(a1[jj][r] + bi));
    }
  }
  __syncthreads();

  // ---- stage 2: K=96 -> C=48 (waves 0..2: j=w; wave 3: zero-fill cols 48..63) ----
  if (wave < 3){
    f32x4 a2 = (f32x4){0.f, 0.f, 0.f, 0.f};
#pragma unroll
    for (int k0 = 0; k0 < 96; k0 += 32){
      int ka = k0 + quad * 8;
      short8 af = *(const short8*)&s1[l15][ka];
      short8 bvv = *(const short8*)(WTA + 176128 + (size_t)(16 * wave + l15) * 96 + ka);
      a2 = __builtin_amdgcn_mfma_f32_16x16x32_bf16(af, bvv, a2, 0, 0, 0);
    }
    int c = 16 * wave + l15;
    float bi = ldp(b2, c, f32);
#pragma unroll
    for (int r = 0; r < 4; ++r)
      s2[quad * 4 + r][c] = f2b(splus(a2[r] + bi));
  } else {
#pragma unroll
    for (int r = 0; r < 4; ++r)
      s2[quad * 4 + r][48 + l15] = f2b(0.f);
  }
  __syncthreads();

  // ---- stage 3: K=64 -> C=32 (waves 0,1: j=w) + dot24 partials ----
  if (wave < 2){
    f32x4 a3 = (f32x4){0.f, 0.f, 0.f, 0.f};
#pragma unroll
    for (int k0 = 0; k0 < 64; k0 += 32){
      int ka = k0 + quad * 8;
      short8 af = *(const short8*)&s2[l15][ka];
      short8 bvv = *(const short8*)(WTA + 182272 + (size_t)(16 * wave + l15) * 64 + ka);
      a3 = __builtin_amdgcn_mfma_f32_16x16x32_bf16(af, bvv, a3, 0, 0, 0);
    }
    int c = 16 * wave + l15;
    float w = (c < 24) ? ldp(w4, c, f32) : 0.f;
    float bi = (c < 24) ? ldp(b3, c, f32) : 0.f;
    float pr[4];
#pragma unroll
    for (int r = 0; r < 4; ++r){
      pr[r] = splus(a3[r] + bi) * w;
#pragma unroll
      for (int o = 1; o < 16; o <<= 1) pr[r] += __shfl_xor(pr[r], o);
      if (l15 == 0) part[wave][quad * 4 + r] = pr[r];
    }
  }
  __syncthreads();
  if (t < 16){
    int n = mbase + t;
    if (n < N){
      float p = 1.f / (1.f + expf(-(part[0][t] + part[1][t] + ldp(b4, 0, f32))));
      long long oi = (long long)N * 192 + n;
      if (f32) ((float*)outfin)[oi] = p; else ((bf16*)outfin)[oi] = f2b(p);
    }
  }
}

// ------------- GCN aggregate via CSR (h bf16) -> BB bf16, + fused att-logit dots -------------
__global__ __launch_bounds__(256) void k_gcn_csr(
    const int* rowptr, const unsigned short* colu, const bf16* h,
    const float* dinv, const void* bias, bf16* outb, int N, int C,
    const bf16* watt, float* asd, const int* flags)
{
  int f32 = flags[0];
  int wid = (blockIdx.x * 256 + threadIdx.x) >> 6;
  int lane = threadIdx.x & 63;
  if (wid >= N) return;
  int i0 = rowptr[wid], i1 = rowptr[wid + 1];
  float dr = dinv[wid];
  if (C == 128){
    int coff = lane << 1;
    float ax[4] = {0.f, 0.f, 0.f, 0.f}, ay[4] = {0.f, 0.f, 0.f, 0.f};
    int i = i0;
    for (; i + 7 < i1; i += 8){
      int s[8];
#pragma unroll
      for (int e = 0; e < 8; ++e) s[e] = colu[i + e];
      bf162 v[8]; float f[8];
#pragma unroll
      for (int e = 0; e < 8; ++e){
        v[e] = *(const bf162*)(h + (size_t)s[e] * 128 + coff);
        f[e] = dinv[s[e]];
      }
#pragma unroll
      for (int e = 0; e < 8; ++e){
        ax[e & 3] = fmaf(f[e], b2f(v[e].x), ax[e & 3]);
        ay[e & 3] = fmaf(f[e], b2f(v[e].y), ay[e & 3]);
      }
    }
    for (; i + 3 < i1; i += 4){
      int s[4] = {colu[i], colu[i + 1], colu[i + 2], colu[i + 3]};
#pragma unroll
      for (int e = 0; e < 4; ++e){
        bf162 v = *(const bf162*)(h + (size_t)s[e] * 128 + coff);
        float f = dinv[s[e]];
        ax[e] = fmaf(f, b2f(v.x), ax[e]); ay[e] = fmaf(f, b2f(v.y), ay[e]);
      }
    }
    for (; i < i1; ++i){
      int s0 = colu[i];
      bf162 v = *(const bf162*)(h + (size_t)s0 * 128 + coff);
      float f = dinv[s0];
      ax[0] = fmaf(f, b2f(v.x), ax[0]); ay[0] = fmaf(f, b2f(v.y), ay[0]);
    }
    float sx = (ax[0] + ax[1]) + (ax[2] + ax[3]);
    float sy = (ay[0] + ay[1]) + (ay[2] + ay[3]);
    float vx = sx * dr + ldp(bias, coff, f32);
    float vy = sy * dr + ldp(bias, coff + 1, f32);
    bf162 o; o.x = f2b(vx); o.y = f2b(vy);
    *(bf162*)(outb + (size_t)wid * 128 + coff) = o;
    if (watt){
      float myv = 0.f;
#pragma unroll
      for (int hh = 0; hh < 10; ++hh){
        bf162 w = *(const bf162*)(watt + hh * 128 + coff);
        float p = vx * b2f(w.x) + vy * b2f(w.y);
#pragma unroll
        for (int o2 = 1; o2 < 64; o2 <<= 1) p += __shfl_xor(p, o2);
        if (lane == hh) myv = p;
      }
      if (lane < 10) asd[(size_t)wid * 10 + lane] = myv;
    }
  } else { // C == 64: half-waves, up to 4 edges per half in flight
    int half = lane >> 5, hl = lane & 31;
    int coff = hl << 1;
    float ax = 0.f, ay = 0.f, bx = 0.f, by = 0.f;
    int i = i0;
    for (; i + 7 < i1; i += 8){
      int sA = colu[i + half],     sB = colu[i + 2 + half];
      int sC = colu[i + 4 + half], sD = colu[i + 6 + half];
      bf162 vA = *(const bf162*)(h + (size_t)sA * 64 + coff);
      bf162 vB = *(const bf162*)(h + (size_t)sB * 64 + coff);
      bf162 vC = *(const bf162*)(h + (size_t)sC * 64 + coff);
      bf162 vD = *(const bf162*)(h + (size_t)sD * 64 + coff);
      float fA = dinv[sA], fB = dinv[sB], fC = dinv[sC], fD = dinv[sD];
      ax = fmaf(fA, b2f(vA.x), ax); ay = fmaf(fA, b2f(vA.y), ay);
      bx = fmaf(fB, b2f(vB.x), bx); by = fmaf(fB, b2f(vB.y), by);
      ax = fmaf(fC, b2f(vC.x), ax); ay = fmaf(fC, b2f(vC.y), ay);
      bx = fmaf(fD, b2f(vD.x), bx); by = fmaf(fD, b2f(vD.y), by);
    }
    for (; i + 3 < i1; i += 4){
      int sA = colu[i + half], sB = colu[i + 2 + half];
      bf162 vA = *(const bf162*)(h + (size_t)sA * 64 + coff);
      bf162 vB = *(const bf162*)(h + (size_t)sB * 64 + coff);
      float fA = dinv[sA], fB = dinv[sB];
      ax = fmaf(fA, b2f(vA.x), ax); ay = fmaf(fA, b2f(vA.y), ay);
      bx = fmaf(fB, b2f(vB.x), bx); by = fmaf(fB, b2f(vB.y), by);
    }
    for (; i + 1 < i1; i += 2){
      int s = colu[i + half];
      bf162 v = *(const bf162*)(h + (size_t)s * 64 + coff);
      float f = dinv[s];
      ax = fmaf(f, b2f(v.x), ax); ay = fmaf(f, b2f(v.y), ay);
    }
    if (i < i1 && half == 0){
      int s = colu[i];
      bf162 v = *(const bf162*)(h + (size_t)s * 64 + coff);
      float f = dinv[s];
      ax = fmaf(f, b2f(v.x), ax); ay = fmaf(f, b2f(v.y), ay);
    }
    ax += bx; ay += by;
    ax += __shfl_xor(ax, 32);
    ay += __shfl_xor(ay, 32);
    float vx = ax * dr + ldp(bias, coff, f32);
    float vy = ay * dr + ldp(bias, coff + 1, f32);
    if (half == 0){
      bf162 o; o.x = f2b(vx); o.y = f2b(vy);
      *(bf162*)(outb + (size_t)wid * 64 + coff) = o;
    }
    if (watt){
      float myv = 0.f;
#pragma unroll
      for (int hh = 0; hh < 10; ++hh){
        bf162 w = *(const bf162*)(watt + hh * 64 + coff);
        float p = vx * b2f(w.x) + vy * b2f(w.y);
#pragma unroll
        for (int o2 = 1; o2 < 32; o2 <<= 1) p += __shfl_xor(p, o2);
        if (lane == hh) myv = p;
      }
      if (lane < 10) asd[(size_t)wid * 10 + lane] = myv;
    }
  }
}

// ------------- FUSED GAT: single-pass unnormalized softmax + alpha-gather (into LDS)
//               + MFMA projection + bias + BN + leaky (+skip) -> d_out;
//               optional gcn2 projection -> hx.
// Block: 16 waves (1024 thr), 16 rows, one row per wave (R10-proven config).
template<int K>
__global__ __launch_bounds__(1024) void k_gat_proj(
    const int* rowptr, const unsigned short* colu, const bf16* bbx,
    const float* asd, const bf16* WT, const void* bias,
    const void* bg, const void* bbp, const void* bm, const void* bv,
    const float* skip, void* dout, int c2off,
    const bf16* WT2, bf16* hx, int N, const int* flags)
{
  constexpr int KP  = HEADS * K;              // 640 / 320
  constexpr int AGP = (K == 128) ? 648 : 328; // row pad: bank offset 4 -> 2-way only
  constexpr int C   = K;
  constexpr int NCG = C / 16;                 // col groups (8 / 4)
  constexpr int KSEG = KP / 2;                // split-K=2 segment (320 / 160)
  __shared__ bf16 agg[16][AGP];
  __shared__ float als[16][HEADS][64];
  __shared__ unsigned short ssrc[16][64];
  int f32 = flags[0];
  int t = threadIdx.x, wave = t >> 6, lane = t & 63;
  int quad = lane >> 4, l15 = lane & 15;
  int rb = blockIdx.x * 16;

  // ---- phase 1: single-pass softmax + gather — wave handles row rb+wave ----
  int wid = rb + wave;
  if (wid < N){
    int i0 = rowptr[wid], i1 = rowptr[wid + 1];
    float adr[HEADS];
#pragma unroll
    for (int h = 0; h < HEADS; ++h) adr[h] = asd[(size_t)wid * 10 + 5 + h];
    float denl[HEADS];
#pragma unroll
    for (int h = 0; h < HEADS; ++h) denl[h] = 0.f;

    if constexpr (K == 128){
      int coff = lane << 1;
      float ax[HEADS], ay[HEADS];
#pragma unroll
      for (int h = 0; h < HEADS; ++h){ ax[h] = 0.f; ay[h] = 0.f; }
      for (int base = i0; base < i1; base += 64){
        int iend = i1 - base; if (iend > 64) iend = 64;
        int i = base + lane;
        if (i < i1){
          int s = colu[i];
          float2 q0 = *(const float2*)(asd + (size_t)s * 10);
          float2 q1 = *(const float2*)(asd + (size_t)s * 10 + 2);
          float q4 = asd[(size_t)s * 10 + 4];
          float w0 = expf(fminf(lrelu(q0.x + adr[0], 0.2f), 80.f));
          float w1 = expf(fminf(lrelu(q0.y + adr[1], 0.2f), 80.f));
          float w2 = expf(fminf(lrelu(q1.x + adr[2], 0.2f), 80.f));
          float w3 = expf(fminf(lrelu(q1.y + adr[3], 0.2f), 80.f));
          float w4 = expf(fminf(lrelu(q4 + adr[4], 0.2f), 80.f));
          ssrc[wave][lane] = (unsigned short)s;
          als[wave][0][lane] = w0; als[wave][1][lane] = w1;
          als[wave][2][lane] = w2; als[wave][3][lane] = w3;
          als[wave][4][lane] = w4;
          denl[0] += w0; denl[1] += w1; denl[2] += w2; denl[3] += w3; denl[4] += w4;
        }
        asm volatile("s_waitcnt lgkmcnt(0)" ::: "memory");
        int j = 0;
        for (; j + 7 < iend; j += 8){
          int s8[8];
#pragma unroll
          for (int e = 0; e < 8; ++e) s8[e] = ssrc[wave][j + e];
          bf162 v[8];
#pragma unroll
          for (int e = 0; e < 8; ++e) v[e] = *(const bf162*)(bbx + (size_t)s8[e] * 128 + coff);
#pragma unroll
          for (int e = 0; e < 8; ++e){
            float fx = b2f(v[e].x), fy = b2f(v[e].y);
#pragma unroll
            for (int h = 0; h < HEADS; ++h){
              float a = als[wave][h][j + e];
              ax[h] = fmaf(a, fx, ax[h]); ay[h] = fmaf(a, fy, ay[h]);
            }
          }
        }
        for (; j + 3 < iend; j += 4){
          int s4[4];
#pragma unroll
          for (int e = 0; e < 4; ++e) s4[e] = ssrc[wave][j + e];
          bf162 v[4];
#pragma unroll
          for (int e = 0; e < 4; ++e) v[e] = *(const bf162*)(bbx + (size_t)s4[e] * 128 + coff);
#pragma unroll
          for (int e = 0; e < 4; ++e){
            float fx = b2f(v[e].x), fy = b2f(v[e].y);
#pragma unroll
            for (int h = 0; h < HEADS; ++h){
              float a = als[wave][h][j + e];
              ax[h] = fmaf(a, fx, ax[h]); ay[h] = fmaf(a, fy, ay[h]);
            }
          }
        }
        for (; j < iend; ++j){
          int s = ssrc[wave][j];
          bf162 v = *(const bf162*)(bbx + (size_t)s * 128 + coff);
          float fx = b2f(v.x), fy = b2f(v.y);
#pragma unroll
          for (int h = 0; h < HEADS; ++h){
            float a = als[wave][h][j];
            ax[h] = fmaf(a, fx, ax[h]); ay[h] = fmaf(a, fy, ay[h]);
          }
        }
      }
      float dnv[HEADS];
#pragma unroll
      for (int h = 0; h < HEADS; ++h){
        float d = denl[h];
        for (int o = 32; o > 0; o >>= 1) d += __shfl_xor(d, o);
        dnv[h] = 1.f / (d * (float)HEADS);
      }
#pragma unroll
      for (int h = 0; h < HEADS; ++h){
        bf162 o; o.x = f2b(ax[h] * dnv[h]); o.y = f2b(ay[h] * dnv[h]);
        *(bf162*)&agg[wave][h * 128 + coff] = o;
      }
    } else { // K == 64: half-waves for gather; softmax on all 64 lanes
      int half = lane >> 5, hl = lane & 31;
      int coff = hl << 1;
      float ax[HEADS], ay[HEADS];
#pragma unroll
      for (int h = 0; h < HEADS; ++h){ ax[h] = 0.f; ay[h] = 0.f; }
      for (int base = i0; base < i1; base += 64){
        int iend = i1 - base; if (iend > 64) iend = 64;
        int i = base + lane;
        if (i < i1){
          int s = colu[i];
          float2 q0 = *(const float2*)(asd + (size_t)s * 10);
          float2 q1 = *(const float2*)(asd + (size_t)s * 10 + 2);
          float q4 = asd[(size_t)s * 10 + 4];
          float w0 = expf(fminf(lrelu(q0.x + adr[0], 0.2f), 80.f));
          float w1 = expf(fminf(lrelu(q0.y + adr[1], 0.2f), 80.f));
          float w2 = expf(fminf(lrelu(q1.x + adr[2], 0.2f), 80.f));
          float w3 = expf(fminf(lrelu(q1.y + adr[3], 0.2f), 80.f));
          float w4 = expf(fminf(lrelu(q4 + adr[4], 0.2f), 80.f));
          ssrc[wave][lane] = (unsigned short)s;
          als[wave][0][lane] = w0; als[wave][1][lane] = w1;
          als[wave][2][lane] = w2; als[wave][3][lane] = w3;
          als[wave][4][lane] = w4;
          denl[0] += w0; denl[1] += w1; denl[2] += w2; denl[3] += w3; denl[4] += w4;
        }
        asm volatile("s_waitcnt lgkmcnt(0)" ::: "memory");
        int j = 0;
        for (; j + 7 < iend; j += 8){
          int sA = ssrc[wave][j + half],     sB = ssrc[wave][j + 2 + half];
          int sC = ssrc[wave][j + 4 + half], sD = ssrc[wave][j + 6 + half];
          bf162 vA = *(const bf162*)(bbx + (size_t)sA * 64 + coff);
          bf162 vB = *(const bf162*)(bbx + (size_t)sB * 64 + coff);
          bf162 vC = *(const bf162*)(bbx + (size_t)sC * 64 + coff);
          bf162 vD = *(const bf162*)(bbx + (size_t)sD * 64 + coff);
          float Ax = b2f(vA.x), Ay = b2f(vA.y), Bx = b2f(vB.x), By = b2f(vB.y);
          float Cx = b2f(vC.x), Cy = b2f(vC.y), Dx = b2f(vD.x), Dy = b2f(vD.y);
#pragma unroll
          for (int h = 0; h < HEADS; ++h){
            float aA = als[wave][h][j + half],     aB = als[wave][h][j + 2 + half];
            float aC = als[wave][h][j + 4 + half], aD = als[wave][h][j + 6 + half];
            ax[h] = fmaf(aA, Ax, ax[h]); ay[h] = fmaf(aA, Ay, ay[h]);
            ax[h] = fmaf(aB, Bx, ax[h]); ay[h] = fmaf(aB, By, ay[h]);
            ax[h] = fmaf(aC, Cx, ax[h]); ay[h] = fmaf(aC, Cy, ay[h]);
            ax[h] = fmaf(aD, Dx, ax[h]); ay[h] = fmaf(aD, Dy, ay[h]);
          }
        }
        for (; j + 3 < iend; j += 4){
          int sA = ssrc[wave][j + half], sB = ssrc[wave][j + 2 + half];
          bf162 vA = *(const bf162*)(bbx + (size_t)sA * 64 + coff);
          bf162 vB = *(const bf162*)(bbx + (size_t)sB * 64 + coff);
          float Ax = b2f(vA.x), Ay = b2f(vA.y), Bx = b2f(vB.x), By = b2f(vB.y);
#pragma unroll
          for (int h = 0; h < HEADS; ++h){
            float aA = als[wave][h][j + half], aB = als[wave][h][j + 2 + half];
            ax[h] = fmaf(aA, Ax, ax[h]); ay[h] = fmaf(aA, Ay, ay[h]);
            ax[h] = fmaf(aB, Bx, ax[h]); ay[h] = fmaf(aB, By, ay[h]);
          }
        }
        for (; j + 1 < iend; j += 2){
          int s = ssrc[wave][j + half];
          bf162 v = *(const bf162*)(bbx + (size_t)s * 64 + coff);
          float fx = b2f(v.x), fy = b2f(v.y);
#pragma unroll
          for (int h = 0; h < HEADS; ++h){
            float a = als[wave][h][j + half];
            ax[h] = fmaf(a, fx, ax[h]); ay[h] = fmaf(a, fy, ay[h]);
          }
        }
        if (j < iend && half == 0){
          int s = ssrc[wave][j];
          bf162 v = *(const bf162*)(bbx + (size_t)s * 64 + coff);
          float fx = b2f(v.x), fy = b2f(v.y);
#pragma unroll
          for (int h = 0; h < HEADS; ++h){
            float a = als[wave][h][j];
            ax[h] = fmaf(a, fx, ax[h]); ay[h] = fmaf(a, fy, ay[h]);
          }
        }
      }
      float dnv[HEADS];
#pragma unroll
      for (int h = 0; h < HEADS; ++h){
        float d = denl[h];
        for (int o = 32; o > 0; o >>= 1) d += __shfl_xor(d, o);
        dnv[h] = 1.f / (d * (float)HEADS);
      }
#pragma unroll
      for (int h = 0; h < HEADS; ++h){
        ax[h] += __shfl_xor(ax[h], 32);
        ay[h] += __shfl_xor(ay[h], 32);
      }
      if (half == 0){
#pragma unroll
        for (int h = 0; h < HEADS; ++h){
          bf162 o; o.x = f2b(ax[h] * dnv[h]); o.y = f2b(ay[h] * dnv[h]);
          *(bf162*)&agg[wave][h * 64 + coff] = o;
        }
      }
    }
  }
  __syncthreads();

  // ---- phase 2: MFMA projection from LDS agg; split-K=2 via LDS reduction ----
  auto red = reinterpret_cast<float(*)[16][20]>(&als[0][0][0]);
  int cg = wave & (NCG - 1);
  int kh = wave / NCG;                 // only kh<2 active
  f32x4 acc = (f32x4){0.f, 0.f, 0.f, 0.f};
  if (kh < 2){
#pragma unroll
    for (int ks = 0; ks < KSEG; ks += 32){
      int ka = kh * KSEG + ks + quad * 8;
      short8 af = *(const short8*)&agg[l15][ka];
      short8 bvv = *(const short8*)(WT + (size_t)(cg * 16 + l15) * KP + ka);
      acc = __builtin_amdgcn_mfma_f32_16x16x32_bf16(af, bvv, acc, 0, 0, 0);
    }
  }
  if (kh == 1){
#pragma unroll
    for (int r = 0; r < 4; ++r)
      red[cg][quad * 4 + r][l15] = acc[r];
  }
  __syncthreads();
  if (kh == 0){
#pragma unroll
    for (int r = 0; r < 4; ++r)
      acc[r] += red[cg][quad * 4 + r][l15];
    int c = cg * 16 + l15;
    float bi = ldp(bias, c, f32);
    float g = ldp(bg, c, f32), be = ldp(bbp, c, f32), mm = ldp(bm, c, f32);
    float iv = rsqrtf(ldp(bv, c, f32) + 1e-5f);
#pragma unroll
    for (int r = 0; r < 4; ++r){
      int n = rb + quad * 4 + r;
      if (n >= N) continue;
      float y = acc[r] + bi;
      y = (y - mm) * iv * g + be;
      y = lrelu(y, 0.01f);
      if (skip) y += skip[(size_t)n * 128 + c];
      size_t o = (size_t)n * 192 + c2off + c;
      if (f32) ((float*)dout)[o] = y; else ((bf16*)dout)[o] = f2b(y);
      if (WT2) agg[quad * 4 + r][c] = f2b(y);   // skip1 tile for gcn2 projection
    }
  }

  // ---- stage 3 (gat1 only): project skip1 tile @ gcn2_w -> hx [N,64] bf16 ----
  if constexpr (K == 128){
    if (WT2){
      __syncthreads();
      int cg2 = wave & 3, kh2 = wave >> 2;   // split-K=4 over 128
      f32x4 a2 = (f32x4){0.f, 0.f, 0.f, 0.f};
      int ka = kh2 * 32 + quad * 8;
      short8 af = *(const short8*)&agg[l15][ka];
      short8 bvv = *(const short8*)(WT2 + (size_t)(cg2 * 16 + l15) * 128 + ka);
      a2 = __builtin_amdgcn_mfma_f32_16x16x32_bf16(af, bvv, a2, 0, 0, 0);
      auto red2 = reinterpret_cast<float(*)[16][20]>(&als[0][0][0]);
      if (kh2 > 0){
        int slot = (kh2 - 1) * 4 + cg2;
#pragma unroll
        for (int r = 0; r < 4; ++r)
          red2[slot][quad * 4 + r][l15] = a2[r];
      }
      __syncthreads();
      if (kh2 == 0){
#pragma unroll
        for (int s = 0; s < 3; ++s)
#pragma unroll
          for (int r = 0; r < 4; ++r)
            a2[r] += red2[s * 4 + cg2][quad * 4 + r][l15];
        int c2 = cg2 * 16 + l15;
#pragma unroll
        for (int r = 0; r < 4; ++r){
          int n = rb + quad * 4 + r;
          if (n < N) hx[(size_t)n * 64 + c2] = f2b(a2[r]);
        }
      }
    }
  }
}

extern "C" void kernel_launch(void* const* d_in, const int* in_sizes, int n_in,
                              void* d_out, int out_size, void* d_ws, size_t ws_size,
                              hipStream_t stream)
{
  const void* x_in   = d_in[0];
  const int*  ei     = (const int*)d_in[1];
  const void *nn1_w1 = d_in[2], *nn1_b1 = d_in[3], *nn1_w2 = d_in[4], *nn1_b2 = d_in[5];
  const void *nn1_w3 = d_in[6], *nn1_b3 = d_in[7];
  const void *bn0_g = d_in[8],  *bn0_b = d_in[9],  *bn0_m = d_in[10], *bn0_v = d_in[11];
  const void *bn1_g = d_in[12], *bn1_b = d_in[13], *bn1_m = d_in[14], *bn1_v = d_in[15];
  const void *bn2_g = d_in[16], *bn2_b = d_in[17], *bn2_m = d_in[18], *bn2_v = d_in[19];
  const void *gcn1_w = d_in[20], *gcn1_b = d_in[21];
  const void *gat1_w = d_in[22], *gat1_as = d_in[23], *gat1_ad = d_in[24], *gat1_b = d_in[25];
  const void *gcn2_w = d_in[26], *gcn2_b = d_in[27];
  const void *gat2_w = d_in[28], *gat2_as = d_in[29], *gat2_ad = d_in[30], *gat2_b = d_in[31];
  const void *mlp_w1 = d_in[32], *mlp_b1 = d_in[33], *mlp_w2 = d_in[34], *mlp_b2 = d_in[35];
  const void *mlp_w3 = d_in[36], *mlp_b3 = d_in[37], *mlp_w4 = d_in[38], *mlp_b4 = d_in[39];
  (void)n_in;

  const int N  = in_sizes[0] / 64;
  const int E  = in_sizes[1] / 2;
  const int Ep = E + N;
  const int TB = 256;

  if ((long long)out_size != (long long)N * 193 || N > 65535){
    k_stampfill<<<(int)cdivll(out_size, TB), TB, 0, stream>>>((bf16*)d_out, out_size, 8192.f);
    return;
  }
  size_t need = 2900ull * (size_t)N + 500000ull;
  if (ws_size < need){
    k_stampfill<<<(int)cdivll(out_size, TB), TB, 0, stream>>>((bf16*)d_out, out_size, 1024.f);
    return;
  }

  // ws layout: flags | X | A | B | DINV | ASD | rowptr | colu(u16) | HX(bf16) | WTA(bf16)
  char* wsb = (char*)d_ws;
  int*   FLAGS = (int*)wsb;
  float* X    = (float*)(wsb + 16);
  float* A    = X + (size_t)N * 128;
  float* B    = A + (size_t)N * 128;
  float* DINV = B + (size_t)N * 128;
  float* AS   = DINV + N;                       // [N][10] f32: a_src(5) | a_dst(5)
  int*   ROWP = (int*)(AS + (size_t)N * 2 * HEADS);
  unsigned short* COLU = (unsigned short*)(ROWP + N + 1);
  bf16*  HX   = (bf16*)(COLU + ((Ep + 7) & ~7)); // gcn projections [N,128]/[N,64] bf16
  bf16*  WTA  = (bf16*)(((uintptr_t)(HX + (size_t)N * 640) + 15) & ~(uintptr_t)15);
  bf16*  BB   = (bf16*)A;    // bf16 GCN output (gat input), aliases A
  int* CNT = (int*)AS;
  int* CUR = CNT + N;
  const int ATT1_OFF = 186368;   // [64][128] folded att weights (gat1)
  const int ATT2_OFF = 194560;   // [64][64]  folded att weights (gat2)

  k_detect<<<1, 256, 0, stream>>>((const unsigned short*)x_in, ei, FLAGS);

  // ---- pack all weights + zero CNT/CUR ----
  PackArgs P;
  P.d[0] = {nn1_w1,  64, 64, 128, 128, 0, 0};
  P.d[1] = {nn1_w2, 128,128,  64,  64, 8192, 0};
  P.d[2] = {nn1_w3,  64, 64, 128, 128, 16384, 0};
  P.d[3] = {gcn1_w, 128,128, 128, 128, 24576, 0};
  P.d[4] = {gat1_w, 128,640, 128, 128, 40960, 5};   // head-folded: [c][h*128+k]
  P.d[5] = {gcn2_w, 128,128,  64,  64, 122880, 0};
  P.d[6] = {gat2_w,  64,320,  64,  64, 131072, 5};  // head-folded: [c][h*64+k]
  P.d[7] = {mlp_w1, 192,192,  96, 128, 151552, 0};
  P.d[8] = {mlp_w2,  96, 96,  48,  64, 176128, 0};
  P.d[9] = {mlp_w3,  48, 64,  24,  64, 182272, 0};
  P.total = 186368;
  k_packall<<<(int)cdivll(P.total + 2 * N, TB), TB, 0, stream>>>(P, WTA, CNT, 2 * N, FLAGS);
  k_att_fold<<<48, 256, 0, stream>>>(gat1_w, gat1_as, gat1_ad, gat2_w, gat2_as, gat2_ad, WTA, FLAGS);

  // ---- CSR build ----
  k_hist<<<(int)cdivll(Ep, TB), TB, 0, stream>>>(ei, E, N, CNT, FLAGS);
  k_scan<<<1, 1024, 0, stream>>>(CNT, ROWP, N);
  k_scatter<<<(int)cdivll(Ep, TB), TB, 0, stream>>>(ei, E, N, ROWP, CUR, COLU, FLAGS);
  k_dinv<<<(int)cdivll(N, TB), TB, 0, stream>>>(ROWP, DINV, N);

  int rowsg = (int)cdivll(N, 4);
  int rows16 = (int)cdivll(N, 16);

  // ---- stage A: fused nn1 MLP (+bn0+leaky) -> X f32, + gcn1 projection -> HX ----
  k_nn1f<<<rows16, 256, 0, stream>>>(x_in, WTA, nn1_b1, nn1_b2, nn1_b3,
                                     bn0_g, bn0_b, bn0_m, bn0_v, X, HX, N, FLAGS);

  // ---- GCN1 aggregate (+att1 logit dots) ----
  k_gcn_csr<<<rowsg, 256, 0, stream>>>(ROWP, COLU, HX, DINV, gcn1_b, BB, N, 128,
                                       WTA + ATT1_OFF, AS, FLAGS);

  // ---- GAT1: softmax+gather+project+bn1+skip -> d_out[:,0:128], + gcn2 proj -> HX[N,64]
  k_gat_proj<128><<<rows16, 1024, 0, stream>>>(ROWP, COLU, BB, AS, WTA + 40960, gat1_b,
      bn1_g, bn1_b, bn1_m, bn1_v, X, d_out, 0, WTA + 122880, HX, N, FLAGS);

  // ---- GCN2 aggregate (+att2 dots) ----
  k_gcn_csr<<<rowsg, 256, 0, stream>>>(ROWP, COLU, HX, DINV, gcn2_b, BB, N, 64,
                                       WTA + ATT2_OFF, AS, FLAGS);

  // ---- GAT2: softmax+gather+project+bn2 -> d_out[:,128:192] ----
  k_gat_proj<64><<<rows16, 1024, 0, stream>>>(ROWP, COLU, BB, AS, WTA + 131072, gat2_b,
      bn2_g, bn2_b, bn2_m, bn2_v, nullptr, d_out, 128, nullptr, nullptr, N, FLAGS);

  // ---- fused node_pred MLP: d_out[N,192] -> probs at d_out[N*192..] ----
  k_mlpf<<<rows16, 256, 0, stream>>>(d_out, WTA, mlp_b1, mlp_b2, mlp_b3,
                                     mlp_w4, mlp_b4, d_out, N, FLAGS);
}

// Round 13
// 407.034 us; speedup vs baseline: 1.0547x; 1.0135x over previous
//
#include <hip/hip_runtime.h>
#include <hip/hip_bf16.h>
#include <math.h>
#include <stdint.h>

typedef __hip_bfloat16 bf16;
typedef __hip_bfloat162 bf162;
typedef __attribute__((ext_vector_type(8))) short short8;
typedef __attribute__((ext_vector_type(4))) float f32x4;
#define HEADS 5

static inline long long cdivll(long long a, long long b){ return (a + b - 1) / b; }

__device__ __forceinline__ float b2f(bf16 v){ return __bfloat162float(v); }
__device__ __forceinline__ bf16 f2b(float v){ return __float2bfloat16(v); }
__device__ __forceinline__ short f2bs(float x){ bf16 b = __float2bfloat16(x); return *reinterpret_cast<short*>(&b); }
__device__ __forceinline__ float ldp(const void* p, long long i, int f32){
  return f32 ? ((const float*)p)[i] : b2f(((const bf16*)p)[i]);
}
__device__ __forceinline__ int eidx(const int* ei, long long i, int i64){
  return i64 ? ei[2 * i] : ei[i];
}
__device__ __forceinline__ float lrelu(float x, float a){ return x >= 0.f ? x : a * x; }
__device__ __forceinline__ float splus(float x){ return fmaxf(x, 0.f) + log1pf(expf(-fabsf(x))); }

// ---------------- runtime dtype detection ----------------
__global__ void k_detect(const unsigned short* xh, const int* ei, int* flags){
  __shared__ int r0[256], r1[256];
  int t = threadIdx.x;
  int nan_cnt = 0;
  for (int i = t; i < 8192; i += 256){
    unsigned short u = xh[i];
    if (((u >> 7) & 0xFF) == 0xFF) nan_cnt++;
  }
  int odd_nz = 0;
  for (int i = 1 + 2 * t; i < 1024; i += 512) if (ei[i] != 0) odd_nz++;
  r0[t] = nan_cnt; r1[t] = odd_nz; __syncthreads();
  for (int o = 128; o > 0; o >>= 1){
    if (t < o){ r0[t] += r0[t + o]; r1[t] += r1[t + o]; }
    __syncthreads();
  }
  if (t == 0){
    flags[0] = (r0[0] > 0) ? 1 : 0;
    flags[1] = (r1[0] == 0) ? 1 : 0;
  }
}

__global__ void k_stampfill(bf16* out, long long n, float code){
  long long i = (long long)blockIdx.x * blockDim.x + threadIdx.x;
  if (i < n) out[i] = f2b(i == 0 ? code : 0.f);
}

// ---------------- CSR build ----------------
__global__ void k_hist(const int* ei, int E, int N, int* counts, const int* flags){
  int i64 = flags[1];
  int e = blockIdx.x * blockDim.x + threadIdx.x;
  if (e >= E + N) return;
  int d = (e < E) ? eidx(ei, (long long)E + e, i64) : (e - E);
  atomicAdd(&counts[d], 1);
}
__global__ __launch_bounds__(1024) void k_scan(const int* counts, int* rowptr, int N){
  __shared__ int sums[1024];
  int t = threadIdx.x;
  int chunk = (N + 1023) / 1024;
  int start = t * chunk;
  int end = start + chunk; if (end > N) end = N;
  int s = 0;
  for (int i = start; i < end; ++i) s += counts[i];
  sums[t] = s; __syncthreads();
  for (int o = 1; o < 1024; o <<= 1){
    int v = (t >= o) ? sums[t - o] : 0;
    __syncthreads();
    sums[t] += v;
    __syncthreads();
  }
  int run = (t == 0) ? 0 : sums[t - 1];
  for (int i = start; i < end; ++i){ rowptr[i] = run; run += counts[i]; }
  if (t == 0) rowptr[N] = sums[1023];
}
// scatter + fused dinv (rowptr final before this launches)
__global__ void k_scatter(const int* ei, int E, int N, const int* rowptr, int* cursor,
                          unsigned short* colu, float* dinv, const int* flags){
  int i64 = flags[1];
  int e = blockIdx.x * blockDim.x + threadIdx.x;
  if (e >= E + N) return;
  if (e < N) dinv[e] = rsqrtf((float)(rowptr[e + 1] - rowptr[e]));
  int s, d;
  if (e < E){ s = eidx(ei, e, i64); d = eidx(ei, (long long)E + e, i64); }
  else { s = d = e - E; }
  int pos = rowptr[d] + atomicAdd(&cursor[d], 1);
  colu[pos] = (unsigned short)s;
}

// ------------- pack ALL weights -> WT arena [c][k]; zero CNT/CUR; fold att weights -------------
// hk != 0: GAT head-fold pack: out[c][h*K + k] = W[k][h*C + c]  (Kp = hk*K, Cp = C)
struct PackDesc { const void* W; int K, Kp, C, Cp, off, hk; };
struct PackArgs { PackDesc d[10]; int total; };
__global__ void k_packall(PackArgs P, bf16* WTA, int* cnt, int ncnt,
                          const void* w1, const void* as1, const void* ad1,
                          const void* w2, const void* as2, const void* ad2,
                          const int* flags){
  int f32 = flags[0];
  int idx = blockIdx.x * blockDim.x + threadIdx.x;
  if (idx >= P.total){
    int z = idx - P.total;
    if (z < ncnt){ cnt[z] = 0; return; }
    int l = z - ncnt;                 // att-fold range [0, 12288)
    if (l < 8192){
      int c = l >> 7, k = l & 127;
      float v = 0.f;
      if (c < 10){
        int h = (c < 5) ? c : c - 5;
        const void* aw = (c < 5) ? as1 : ad1;
        for (int j = 0; j < 128; ++j)
          v = fmaf(ldp(w1, (long long)k * 640 + h * 128 + j, f32), ldp(aw, h * 128 + j, f32), v);
      }
      WTA[186368 + l] = f2b(v);
    } else if (l < 12288){
      int l2 = l - 8192;
      int c = l2 >> 6, k = l2 & 63;
      float v = 0.f;
      if (c < 10){
        int h = (c < 5) ? c : c - 5;
        const void* aw = (c < 5) ? as2 : ad2;
        for (int j = 0; j < 64; ++j)
          v = fmaf(ldp(w2, (long long)k * 320 + h * 64 + j, f32), ldp(aw, h * 64 + j, f32), v);
      }
      WTA[194560 + l2] = f2b(v);
    }
    return;
  }
  int base = 0;
#pragma unroll
  for (int s = 0; s < 10; ++s){
    int sz = P.d[s].Kp * P.d[s].Cp;
    if (idx < base + sz){
      int local = idx - base;
      int c = local / P.d[s].Kp;
      int k = local - c * P.d[s].Kp;
      float v;
      if (P.d[s].hk){
        int h = k / P.d[s].K;
        int kk = k - h * P.d[s].K;
        v = (c < P.d[s].C)
          ? ldp(P.d[s].W, (long long)kk * (P.d[s].hk * P.d[s].C) + h * P.d[s].C + c, f32) : 0.f;
      } else {
        v = (k < P.d[s].K && c < P.d[s].C)
          ? ldp(P.d[s].W, (long long)k * P.d[s].C + c, f32) : 0.f;
      }
      WTA[P.d[s].off + local] = f2b(v);
      return;
    }
    base += sz;
  }
}

// ------------- fused nn1 MLP, 16 rows/block, col-split across 4 waves:
//   x_in[N,64] -> softplus -> [N,128] -> softplus -> [N,64] -> bn0+leaky -> X[N,128] f32
//   AND gcn1 projection (pre-scaled by dinv[n]) -> HX[N,128] bf16.
__global__ __launch_bounds__(256) void k_nn1f(
    const void* xin, const bf16* WTA,
    const void* b1, const void* b2, const void* b3,
    const void* g0, const void* bb0, const void* m0, const void* v0,
    const float* dinv, float* X, bf16* hx, int N, const int* flags)
{
  __shared__ bf16 s1[16][136];
  __shared__ bf16 s2[16][72];
  int f32 = flags[0];
  int t = threadIdx.x, wave = t >> 6, lane = t & 63;
  int quad = lane >> 4, l15 = lane & 15;
  int mbase = blockIdx.x * 16;
  int m = mbase + l15; if (m > N - 1) m = N - 1;

  // ---- stage 1: K=64 -> C=128 (wave w: j = 2w, 2w+1) ----
  f32x4 a1[2];
#pragma unroll
  for (int j = 0; j < 2; ++j) a1[j] = (f32x4){0.f, 0.f, 0.f, 0.f};
#pragma unroll
  for (int k0 = 0; k0 < 64; k0 += 32){
    int ka = k0 + quad * 8;
    short8 af;
    if (!f32){
      af = *(const short8*)((const bf16*)xin + (size_t)m * 64 + ka);
    } else {
      const float* p = (const float*)xin + (size_t)m * 64 + ka;
      float4 v0v = *(const float4*)p;
      float4 v1v = *(const float4*)(p + 4);
      af[0] = f2bs(v0v.x); af[1] = f2bs(v0v.y); af[2] = f2bs(v0v.z); af[3] = f2bs(v0v.w);
      af[4] = f2bs(v1v.x); af[5] = f2bs(v1v.y); af[6] = f2bs(v1v.z); af[7] = f2bs(v1v.w);
    }
#pragma unroll
    for (int jj = 0; jj < 2; ++jj){
      int j = wave * 2 + jj;
      short8 bvv = *(const short8*)(WTA + (size_t)(16 * j + l15) * 64 + ka);
      a1[jj] = __builtin_amdgcn_mfma_f32_16x16x32_bf16(af, bvv, a1[jj], 0, 0, 0);
    }
  }
#pragma unroll
  for (int jj = 0; jj < 2; ++jj){
    int c = 16 * (wave * 2 + jj) + l15;
    float bi = ldp(b1, c, f32);
#pragma unroll
    for (int r = 0; r < 4; ++r)
      s1[quad * 4 + r][c] = f2b(splus(a1[jj][r] + bi));
  }
  __syncthreads();

  // ---- stage 2: K=128 -> C=64 (wave w: j = w) ----
  f32x4 a2 = (f32x4){0.f, 0.f, 0.f, 0.f};
#pragma unroll
  for (int k0 = 0; k0 < 128; k0 += 32){
    int ka = k0 + quad * 8;
    short8 af = *(const short8*)&s1[l15][ka];
    short8 bvv = *(const short8*)(WTA + 8192 + (size_t)(16 * wave + l15) * 128 + ka);
    a2 = __builtin_amdgcn_mfma_f32_16x16x32_bf16(af, bvv, a2, 0, 0, 0);
  }
  {
    int c = 16 * wave + l15;
    float bi = ldp(b2, c, f32);
#pragma unroll
    for (int r = 0; r < 4; ++r)
      s2[quad * 4 + r][c] = f2b(splus(a2[r] + bi));
  }
  __syncthreads();

  // ---- stage 3: K=64 -> C=128, bn0+leaky -> X f32 + s1 (dead buffer) ----
  f32x4 a3[2];
#pragma unroll
  for (int j = 0; j < 2; ++j) a3[j] = (f32x4){0.f, 0.f, 0.f, 0.f};
#pragma unroll
  for (int k0 = 0; k0 < 64; k0 += 32){
    int ka = k0 + quad * 8;
    short8 af = *(const short8*)&s2[l15][ka];
#pragma unroll
    for (int jj = 0; jj < 2; ++jj){
      int j = wave * 2 + jj;
      short8 bvv = *(const short8*)(WTA + 16384 + (size_t)(16 * j + l15) * 64 + ka);
      a3[jj] = __builtin_amdgcn_mfma_f32_16x16x32_bf16(af, bvv, a3[jj], 0, 0, 0);
    }
  }
#pragma unroll
  for (int jj = 0; jj < 2; ++jj){
    int c = 16 * (wave * 2 + jj) + l15;
    float bi = ldp(b3, c, f32);
    float g = ldp(g0, c, f32), be = ldp(bb0, c, f32), mm = ldp(m0, c, f32);
    float iv = rsqrtf(ldp(v0, c, f32) + 1e-5f);
#pragma unroll
    for (int r = 0; r < 4; ++r){
      int n = mbase + quad * 4 + r;
      float y = a3[jj][r] + bi;
      y = (y - mm) * iv * g + be;
      y = lrelu(y, 0.01f);
      if (n < N) X[(size_t)n * 128 + c] = y;
      s1[quad * 4 + r][c] = f2b(y);
    }
  }
  __syncthreads();

  // ---- stage 4: gcn1 projection K=128 -> C=128, pre-scaled by dinv[n] -> HX bf16 ----
  f32x4 a4[2];
#pragma unroll
  for (int j = 0; j < 2; ++j) a4[j] = (f32x4){0.f, 0.f, 0.f, 0.f};
#pragma unroll
  for (int k0 = 0; k0 < 128; k0 += 32){
    int ka = k0 + quad * 8;
    short8 af = *(const short8*)&s1[l15][ka];
#pragma unroll
    for (int jj = 0; jj < 2; ++jj){
      int j = wave * 2 + jj;
      short8 bvv = *(const short8*)(WTA + 24576 + (size_t)(16 * j + l15) * 128 + ka);
      a4[jj] = __builtin_amdgcn_mfma_f32_16x16x32_bf16(af, bvv, a4[jj], 0, 0, 0);
    }
  }
#pragma unroll
  for (int jj = 0; jj < 2; ++jj){
    int c = 16 * (wave * 2 + jj) + l15;
#pragma unroll
    for (int r = 0; r < 4; ++r){
      int n = mbase + quad * 4 + r;
      if (n < N) hx[(size_t)n * 128 + c] = f2b(a4[jj][r] * dinv[n]);
    }
  }
}

// ------------- fused node_pred MLP, 16 rows/block, col-split across 4 waves:
//   d_out[N,192] -> 96 -> 48 -> 24 -> dot24+sigmoid -> d_out[N*192 + n].
__global__ __launch_bounds__(256) void k_mlpf(
    const void* dout, const bf16* WTA,
    const void* b1, const void* b2, const void* b3,
    const void* w4, const void* b4, void* outfin, int N, const int* flags)
{
  __shared__ bf16 s1[16][104];
  __shared__ bf16 s2[16][72];
  __shared__ float part[2][16];
  int f32 = flags[0];
  int t = threadIdx.x, wave = t >> 6, lane = t & 63;
  int quad = lane >> 4, l15 = lane & 15;
  int mbase = blockIdx.x * 16;
  int m = mbase + l15; if (m > N - 1) m = N - 1;

  // ---- stage 1: K=192 -> C=96 (wave w: j = w and w+4 if <6) ----
  f32x4 a1[2];
#pragma unroll
  for (int j = 0; j < 2; ++j) a1[j] = (f32x4){0.f, 0.f, 0.f, 0.f};
#pragma unroll
  for (int k0 = 0; k0 < 192; k0 += 32){
    int ka = k0 + quad * 8;
    short8 af;
    if (!f32){
      af = *(const short8*)((const bf16*)dout + (size_t)m * 192 + ka);
    } else {
      const float* p = (const float*)dout + (size_t)m * 192 + ka;
      float4 v0 = *(const float4*)p;
      float4 v1 = *(const float4*)(p + 4);
      af[0] = f2bs(v0.x); af[1] = f2bs(v0.y); af[2] = f2bs(v0.z); af[3] = f2bs(v0.w);
      af[4] = f2bs(v1.x); af[5] = f2bs(v1.y); af[6] = f2bs(v1.z); af[7] = f2bs(v1.w);
    }
#pragma unroll
    for (int jj = 0; jj < 2; ++jj){
      int j = wave + 4 * jj;
      if (j < 6){
        short8 bvv = *(const short8*)(WTA + 151552 + (size_t)(16 * j + l15) * 192 + ka);
        a1[jj] = __builtin_amdgcn_mfma_f32_16x16x32_bf16(af, bvv, a1[jj], 0, 0, 0);
      }
    }
  }
#pragma unroll
  for (int jj = 0; jj < 2; ++jj){
    int j = wave + 4 * jj;
    if (j < 6){
      int c = 16 * j + l15;
      float bi = ldp(b1, c, f32);
#pragma unroll
      for (int r = 0; r < 4; ++r)
        s1[quad * 4 + r][c] = f2b(splus(a1[jj][r] + bi));
    }
  }
  __syncthreads();

  // ---- stage 2: K=96 -> C=48 (waves 0..2: j=w; wave 3: zero-fill cols 48..63) ----
  if (wave < 3){
    f32x4 a2 = (f32x4){0.f, 0.f, 0.f, 0.f};
#pragma unroll
    for (int k0 = 0; k0 < 96; k0 += 32){
      int ka = k0 + quad * 8;
      short8 af = *(const short8*)&s1[l15][ka];
      short8 bvv = *(const short8*)(WTA + 176128 + (size_t)(16 * wave + l15) * 96 + ka);
      a2 = __builtin_amdgcn_mfma_f32_16x16x32_bf16(af, bvv, a2, 0, 0, 0);
    }
    int c = 16 * wave + l15;
    float bi = ldp(b2, c, f32);
#pragma unroll
    for (int r = 0; r < 4; ++r)
      s2[quad * 4 + r][c] = f2b(splus(a2[r] + bi));
  } else {
#pragma unroll
    for (int r = 0; r < 4; ++r)
      s2[quad * 4 + r][48 + l15] = f2b(0.f);
  }
  __syncthreads();

  // ---- stage 3: K=64 -> C=32 (waves 0,1: j=w) + dot24 partials ----
  if (wave < 2){
    f32x4 a3 = (f32x4){0.f, 0.f, 0.f, 0.f};
#pragma unroll
    for (int k0 = 0; k0 < 64; k0 += 32){
      int ka = k0 + quad * 8;
      short8 af = *(const short8*)&s2[l15][ka];
      short8 bvv = *(const short8*)(WTA + 182272 + (size_t)(16 * wave + l15) * 64 + ka);
      a3 = __builtin_amdgcn_mfma_f32_16x16x32_bf16(af, bvv, a3, 0, 0, 0);
    }
    int c = 16 * wave + l15;
    float w = (c < 24) ? ldp(w4, c, f32) : 0.f;
    float bi = (c < 24) ? ldp(b3, c, f32) : 0.f;
    float pr[4];
#pragma unroll
    for (int r = 0; r < 4; ++r){
      pr[r] = splus(a3[r] + bi) * w;
#pragma unroll
      for (int o = 1; o < 16; o <<= 1) pr[r] += __shfl_xor(pr[r], o);
      if (l15 == 0) part[wave][quad * 4 + r] = pr[r];
    }
  }
  __syncthreads();
  if (t < 16){
    int n = mbase + t;
    if (n < N){
      float p = 1.f / (1.f + expf(-(part[0][t] + part[1][t] + ldp(b4, 0, f32))));
      long long oi = (long long)N * 192 + n;
      if (f32) ((float*)outfin)[oi] = p; else ((bf16*)outfin)[oi] = f2b(p);
    }
  }
}

// ------------- GCN aggregate via CSR (h bf16, PRE-SCALED by dinv[s]) -> BB bf16,
//               + fused att-logit dots -------------
__global__ __launch_bounds__(256) void k_gcn_csr(
    const int* rowptr, const unsigned short* colu, const bf16* h,
    const float* dinv, const void* bias, bf16* outb, int N, int C,
    const bf16* watt, float* asd, const int* flags)
{
  int f32 = flags[0];
  int wid = (blockIdx.x * 256 + threadIdx.x) >> 6;
  int lane = threadIdx.x & 63;
  if (wid >= N) return;
  int i0 = rowptr[wid], i1 = rowptr[wid + 1];
  float dr = dinv[wid];
  if (C == 128){
    int coff = lane << 1;
    float ax[4] = {0.f, 0.f, 0.f, 0.f}, ay[4] = {0.f, 0.f, 0.f, 0.f};
    int i = i0;
    for (; i + 7 < i1; i += 8){
      int s[8];
#pragma unroll
      for (int e = 0; e < 8; ++e) s[e] = colu[i + e];
      bf162 v[8];
#pragma unroll
      for (int e = 0; e < 8; ++e)
        v[e] = *(const bf162*)(h + (size_t)s[e] * 128 + coff);
#pragma unroll
      for (int e = 0; e < 8; ++e){
        ax[e & 3] += b2f(v[e].x);
        ay[e & 3] += b2f(v[e].y);
      }
    }
    for (; i + 3 < i1; i += 4){
      int s[4] = {colu[i], colu[i + 1], colu[i + 2], colu[i + 3]};
#pragma unroll
      for (int e = 0; e < 4; ++e){
        bf162 v = *(const bf162*)(h + (size_t)s[e] * 128 + coff);
        ax[e] += b2f(v.x); ay[e] += b2f(v.y);
      }
    }
    for (; i < i1; ++i){
      int s0 = colu[i];
      bf162 v = *(const bf162*)(h + (size_t)s0 * 128 + coff);
      ax[0] += b2f(v.x); ay[0] += b2f(v.y);
    }
    float sx = (ax[0] + ax[1]) + (ax[2] + ax[3]);
    float sy = (ay[0] + ay[1]) + (ay[2] + ay[3]);
    float vx = sx * dr + ldp(bias, coff, f32);
    float vy = sy * dr + ldp(bias, coff + 1, f32);
    bf162 o; o.x = f2b(vx); o.y = f2b(vy);
    *(bf162*)(outb + (size_t)wid * 128 + coff) = o;
    if (watt){
      float myv = 0.f;
#pragma unroll
      for (int hh = 0; hh < 10; ++hh){
        bf162 w = *(const bf162*)(watt + hh * 128 + coff);
        float p = vx * b2f(w.x) + vy * b2f(w.y);
#pragma unroll
        for (int o2 = 1; o2 < 64; o2 <<= 1) p += __shfl_xor(p, o2);
        if (lane == hh) myv = p;
      }
      if (lane < 10) asd[(size_t)wid * 10 + lane] = myv;
    }
  } else { // C == 64: half-waves, up to 4 edges per half in flight
    int half = lane >> 5, hl = lane & 31;
    int coff = hl << 1;
    float ax = 0.f, ay = 0.f, bx = 0.f, by = 0.f;
    int i = i0;
    for (; i + 7 < i1; i += 8){
      int sA = colu[i + half],     sB = colu[i + 2 + half];
      int sC = colu[i + 4 + half], sD = colu[i + 6 + half];
      bf162 vA = *(const bf162*)(h + (size_t)sA * 64 + coff);
      bf162 vB = *(const bf162*)(h + (size_t)sB * 64 + coff);
      bf162 vC = *(const bf162*)(h + (size_t)sC * 64 + coff);
      bf162 vD = *(const bf162*)(h + (size_t)sD * 64 + coff);
      ax += b2f(vA.x); ay += b2f(vA.y);
      bx += b2f(vB.x); by += b2f(vB.y);
      ax += b2f(vC.x); ay += b2f(vC.y);
      bx += b2f(vD.x); by += b2f(vD.y);
    }
    for (; i + 3 < i1; i += 4){
      int sA = colu[i + half], sB = colu[i + 2 + half];
      bf162 vA = *(const bf162*)(h + (size_t)sA * 64 + coff);
      bf162 vB = *(const bf162*)(h + (size_t)sB * 64 + coff);
      ax += b2f(vA.x); ay += b2f(vA.y);
      bx += b2f(vB.x); by += b2f(vB.y);
    }
    for (; i + 1 < i1; i += 2){
      int s = colu[i + half];
      bf162 v = *(const bf162*)(h + (size_t)s * 64 + coff);
      ax += b2f(v.x); ay += b2f(v.y);
    }
    if (i < i1 && half == 0){
      int s = colu[i];
      bf162 v = *(const bf162*)(h + (size_t)s * 64 + coff);
      ax += b2f(v.x); ay += b2f(v.y);
    }
    ax += bx; ay += by;
    ax += __shfl_xor(ax, 32);
    ay += __shfl_xor(ay, 32);
    float vx = ax * dr + ldp(bias, coff, f32);
    float vy = ay * dr + ldp(bias, coff + 1, f32);
    if (half == 0){
      bf162 o; o.x = f2b(vx); o.y = f2b(vy);
      *(bf162*)(outb + (size_t)wid * 64 + coff) = o;
    }
    if (watt){
      float myv = 0.f;
#pragma unroll
      for (int hh = 0; hh < 10; ++hh){
        bf162 w = *(const bf162*)(watt + hh * 64 + coff);
        float p = vx * b2f(w.x) + vy * b2f(w.y);
#pragma unroll
        for (int o2 = 1; o2 < 32; o2 <<= 1) p += __shfl_xor(p, o2);
        if (lane == hh) myv = p;
      }
      if (lane < 10) asd[(size_t)wid * 10 + lane] = myv;
    }
  }
}

// ------------- FUSED GAT: single-pass unnormalized softmax + alpha-gather (into LDS)
//               + MFMA projection + bias + BN + leaky (+skip) -> d_out;
//               optional gcn2 projection (pre-scaled by dinv) -> hx.
// Block: 16 waves (1024 thr), 16 rows, one row per wave (proven config).
template<int K>
__global__ __launch_bounds__(1024) void k_gat_proj(
    const int* rowptr, const unsigned short* colu, const bf16* bbx,
    const float* asd, const bf16* WT, const void* bias,
    const void* bg, const void* bbp, const void* bm, const void* bv,
    const float* skip, void* dout, int c2off,
    const bf16* WT2, bf16* hx, const float* dinvp, int N, const int* flags)
{
  constexpr int KP  = HEADS * K;              // 640 / 320
  constexpr int AGP = (K == 128) ? 648 : 328; // row pad: bank offset 4 -> 2-way only
  constexpr int C   = K;
  constexpr int NCG = C / 16;                 // col groups (8 / 4)
  constexpr int KSEG = KP / 2;                // split-K=2 segment (320 / 160)
  __shared__ bf16 agg[16][AGP];
  __shared__ float als[16][HEADS][64];
  __shared__ unsigned short ssrc[16][64];
  int f32 = flags[0];
  int t = threadIdx.x, wave = t >> 6, lane = t & 63;
  int quad = lane >> 4, l15 = lane & 15;
  int rb = blockIdx.x * 16;

  // ---- phase 1: single-pass softmax + gather — wave handles row rb+wave ----
  int wid = rb + wave;
  if (wid < N){
    int i0 = rowptr[wid], i1 = rowptr[wid + 1];
    float adr[HEADS];
#pragma unroll
    for (int h = 0; h < HEADS; ++h) adr[h] = asd[(size_t)wid * 10 + 5 + h];
    float denl[HEADS];
#pragma unroll
    for (int h = 0; h < HEADS; ++h) denl[h] = 0.f;

    if constexpr (K == 128){
      int coff = lane << 1;
      float ax[HEADS], ay[HEADS];
#pragma unroll
      for (int h = 0; h < HEADS; ++h){ ax[h] = 0.f; ay[h] = 0.f; }
      for (int base = i0; base < i1; base += 64){
        int iend = i1 - base; if (iend > 64) iend = 64;
        int i = base + lane;
        if (i < i1){
          int s = colu[i];
          float2 q0 = *(const float2*)(asd + (size_t)s * 10);
          float2 q1 = *(const float2*)(asd + (size_t)s * 10 + 2);
          float q4 = asd[(size_t)s * 10 + 4];
          float w0 = expf(fminf(lrelu(q0.x + adr[0], 0.2f), 80.f));
          float w1 = expf(fminf(lrelu(q0.y + adr[1], 0.2f), 80.f));
          float w2 = expf(fminf(lrelu(q1.x + adr[2], 0.2f), 80.f));
          float w3 = expf(fminf(lrelu(q1.y + adr[3], 0.2f), 80.f));
          float w4 = expf(fminf(lrelu(q4 + adr[4], 0.2f), 80.f));
          ssrc[wave][lane] = (unsigned short)s;
          als[wave][0][lane] = w0; als[wave][1][lane] = w1;
          als[wave][2][lane] = w2; als[wave][3][lane] = w3;
          als[wave][4][lane] = w4;
          denl[0] += w0; denl[1] += w1; denl[2] += w2; denl[3] += w3; denl[4] += w4;
        }
        asm volatile("s_waitcnt lgkmcnt(0)" ::: "memory");
        int j = 0;
        for (; j + 7 < iend; j += 8){
          int s8[8];
#pragma unroll
          for (int e = 0; e < 8; ++e) s8[e] = ssrc[wave][j + e];
          bf162 v[8];
#pragma unroll
          for (int e = 0; e < 8; ++e) v[e] = *(const bf162*)(bbx + (size_t)s8[e] * 128 + coff);
#pragma unroll
          for (int e = 0; e < 8; ++e){
            float fx = b2f(v[e].x), fy = b2f(v[e].y);
#pragma unroll
            for (int h = 0; h < HEADS; ++h){
              float a = als[wave][h][j + e];
              ax[h] = fmaf(a, fx, ax[h]); ay[h] = fmaf(a, fy, ay[h]);
            }
          }
        }
        for (; j + 3 < iend; j += 4){
          int s4[4];
#pragma unroll
          for (int e = 0; e < 4; ++e) s4[e] = ssrc[wave][j + e];
          bf162 v[4];
#pragma unroll
          for (int e = 0; e < 4; ++e) v[e] = *(const bf162*)(bbx + (size_t)s4[e] * 128 + coff);
#pragma unroll
          for (int e = 0; e < 4; ++e){
            float fx = b2f(v[e].x), fy = b2f(v[e].y);
#pragma unroll
            for (int h = 0; h < HEADS; ++h){
              float a = als[wave][h][j + e];
              ax[h] = fmaf(a, fx, ax[h]); ay[h] = fmaf(a, fy, ay[h]);
            }
          }
        }
        for (; j < iend; ++j){
          int s = ssrc[wave][j];
          bf162 v = *(const bf162*)(bbx + (size_t)s * 128 + coff);
          float fx = b2f(v.x), fy = b2f(v.y);
#pragma unroll
          for (int h = 0; h < HEADS; ++h){
            float a = als[wave][h][j];
            ax[h] = fmaf(a, fx, ax[h]); ay[h] = fmaf(a, fy, ay[h]);
          }
        }
      }
      float dnv[HEADS];
#pragma unroll
      for (int h = 0; h < HEADS; ++h){
        float d = denl[h];
        for (int o = 32; o > 0; o >>= 1) d += __shfl_xor(d, o);
        dnv[h] = 1.f / (d * (float)HEADS);
      }
#pragma unroll
      for (int h = 0; h < HEADS; ++h){
        bf162 o; o.x = f2b(ax[h] * dnv[h]); o.y = f2b(ay[h] * dnv[h]);
        *(bf162*)&agg[wave][h * 128 + coff] = o;
      }
    } else { // K == 64: half-waves for gather; softmax on all 64 lanes
      int half = lane >> 5, hl = lane & 31;
      int coff = hl << 1;
      float ax[HEADS], ay[HEADS];
#pragma unroll
      for (int h = 0; h < HEADS; ++h){ ax[h] = 0.f; ay[h] = 0.f; }
      for (int base = i0; base < i1; base += 64){
        int iend = i1 - base; if (iend > 64) iend = 64;
        int i = base + lane;
        if (i < i1){
          int s = colu[i];
          float2 q0 = *(const float2*)(asd + (size_t)s * 10);
          float2 q1 = *(const float2*)(asd + (size_t)s * 10 + 2);
          float q4 = asd[(size_t)s * 10 + 4];
          float w0 = expf(fminf(lrelu(q0.x + adr[0], 0.2f), 80.f));
          float w1 = expf(fminf(lrelu(q0.y + adr[1], 0.2f), 80.f));
          float w2 = expf(fminf(lrelu(q1.x + adr[2], 0.2f), 80.f));
          float w3 = expf(fminf(lrelu(q1.y + adr[3], 0.2f), 80.f));
          float w4 = expf(fminf(lrelu(q4 + adr[4], 0.2f), 80.f));
          ssrc[wave][lane] = (unsigned short)s;
          als[wave][0][lane] = w0; als[wave][1][lane] = w1;
          als[wave][2][lane] = w2; als[wave][3][lane] = w3;
          als[wave][4][lane] = w4;
          denl[0] += w0; denl[1] += w1; denl[2] += w2; denl[3] += w3; denl[4] += w4;
        }
        asm volatile("s_waitcnt lgkmcnt(0)" ::: "memory");
        int j = 0;
        for (; j + 7 < iend; j += 8){
          int sA = ssrc[wave][j + half],     sB = ssrc[wave][j + 2 + half];
          int sC = ssrc[wave][j + 4 + half], sD = ssrc[wave][j + 6 + half];
          bf162 vA = *(const bf162*)(bbx + (size_t)sA * 64 + coff);
          bf162 vB = *(const bf162*)(bbx + (size_t)sB * 64 + coff);
          bf162 vC = *(const bf162*)(bbx + (size_t)sC * 64 + coff);
          bf162 vD = *(const bf162*)(bbx + (size_t)sD * 64 + coff);
          float Ax = b2f(vA.x), Ay = b2f(vA.y), Bx = b2f(vB.x), By = b2f(vB.y);
          float Cx = b2f(vC.x), Cy = b2f(vC.y), Dx = b2f(vD.x), Dy = b2f(vD.y);
#pragma unroll
          for (int h = 0; h < HEADS; ++h){
            float aA = als[wave][h][j + half],     aB = als[wave][h][j + 2 + half];
            float aC = als[wave][h][j + 4 + half], aD = als[wave][h][j + 6 + half];
            ax[h] = fmaf(aA, Ax, ax[h]); ay[h] = fmaf(aA, Ay, ay[h]);
            ax[h] = fmaf(aB, Bx, ax[h]); ay[h] = fmaf(aB, By, ay[h]);
            ax[h] = fmaf(aC, Cx, ax[h]); ay[h] = fmaf(aC, Cy, ay[h]);
            ax[h] = fmaf(aD, Dx, ax[h]); ay[h] = fmaf(aD, Dy, ay[h]);
          }
        }
        for (; j + 3 < iend; j += 4){
          int sA = ssrc[wave][j + half], sB = ssrc[wave][j + 2 + half];
          bf162 vA = *(const bf162*)(bbx + (size_t)sA * 64 + coff);
          bf162 vB = *(const bf162*)(bbx + (size_t)sB * 64 + coff);
          float Ax = b2f(vA.x), Ay = b2f(vA.y), Bx = b2f(vB.x), By = b2f(vB.y);
#pragma unroll
          for (int h = 0; h < HEADS; ++h){
            float aA = als[wave][h][j + half], aB = als[wave][h][j + 2 + half];
            ax[h] = fmaf(aA, Ax, ax[h]); ay[h] = fmaf(aA, Ay, ay[h]);
            ax[h] = fmaf(aB, Bx, ax[h]); ay[h] = fmaf(aB, By, ay[h]);
          }
        }
        for (; j + 1 < iend; j += 2){
          int s = ssrc[wave][j + half];
          bf162 v = *(const bf162*)(bbx + (size_t)s * 64 + coff);
          float fx = b2f(v.x), fy = b2f(v.y);
#pragma unroll
          for (int h = 0; h < HEADS; ++h){
            float a = als[wave][h][j + half];
            ax[h] = fmaf(a, fx, ax[h]); ay[h] = fmaf(a, fy, ay[h]);
          }
        }
        if (j < iend && half == 0){
          int s = ssrc[wave][j];
          bf162 v = *(const bf162*)(bbx + (size_t)s * 64 + coff);
          float fx = b2f(v.x), fy = b2f(v.y);
#pragma unroll
          for (int h = 0; h < HEADS; ++h){
            float a = als[wave][h][j];
            ax[h] = fmaf(a, fx, ax[h]); ay[h] = fmaf(a, fy, ay[h]);
          }
        }
      }
      float dnv[HEADS];
#pragma unroll
      for (int h = 0; h < HEADS; ++h){
        float d = denl[h];
        for (int o = 32; o > 0; o >>= 1) d += __shfl_xor(d, o);
        dnv[h] = 1.f / (d * (float)HEADS);
      }
#pragma unroll
      for (int h = 0; h < HEADS; ++h){
        ax[h] += __shfl_xor(ax[h], 32);
        ay[h] += __shfl_xor(ay[h], 32);
      }
      if (half == 0){
#pragma unroll
        for (int h = 0; h < HEADS; ++h){
          bf162 o; o.x = f2b(ax[h] * dnv[h]); o.y = f2b(ay[h] * dnv[h]);
          *(bf162*)&agg[wave][h * 64 + coff] = o;
        }
      }
    }
  }
  __syncthreads();

  // ---- phase 2: MFMA projection from LDS agg; split-K=2 via LDS reduction ----
  auto red = reinterpret_cast<float(*)[16][20]>(&als[0][0][0]);
  int cg = wave & (NCG - 1);
  int kh = wave / NCG;                 // only kh<2 active
  f32x4 acc = (f32x4){0.f, 0.f, 0.f, 0.f};
  if (kh < 2){
#pragma unroll
    for (int ks = 0; ks < KSEG; ks += 32){
      int ka = kh * KSEG + ks + quad * 8;
      short8 af = *(const short8*)&agg[l15][ka];
      short8 bvv = *(const short8*)(WT + (size_t)(cg * 16 + l15) * KP + ka);
      acc = __builtin_amdgcn_mfma_f32_16x16x32_bf16(af, bvv, acc, 0, 0, 0);
    }
  }
  if (kh == 1){
#pragma unroll
    for (int r = 0; r < 4; ++r)
      red[cg][quad * 4 + r][l15] = acc[r];
  }
  __syncthreads();
  if (kh == 0){
#pragma unroll
    for (int r = 0; r < 4; ++r)
      acc[r] += red[cg][quad * 4 + r][l15];
    int c = cg * 16 + l15;
    float bi = ldp(bias, c, f32);
    float g = ldp(bg, c, f32), be = ldp(bbp, c, f32), mm = ldp(bm, c, f32);
    float iv = rsqrtf(ldp(bv, c, f32) + 1e-5f);
#pragma unroll
    for (int r = 0; r < 4; ++r){
      int n = rb + quad * 4 + r;
      if (n >= N) continue;
      float y = acc[r] + bi;
      y = (y - mm) * iv * g + be;
      y = lrelu(y, 0.01f);
      if (skip) y += skip[(size_t)n * 128 + c];
      size_t o = (size_t)n * 192 + c2off + c;
      if (f32) ((float*)dout)[o] = y; else ((bf16*)dout)[o] = f2b(y);
      if (WT2) agg[quad * 4 + r][c] = f2b(y);   // skip1 tile for gcn2 projection
    }
  }

  // ---- stage 3 (gat1 only): project skip1 tile @ gcn2_w, pre-scale by dinv -> hx ----
  if constexpr (K == 128){
    if (WT2){
      __syncthreads();
      int cg2 = wave & 3, kh2 = wave >> 2;   // split-K=4 over 128
      f32x4 a2 = (f32x4){0.f, 0.f, 0.f, 0.f};
      int ka = kh2 * 32 + quad * 8;
      short8 af = *(const short8*)&agg[l15][ka];
      short8 bvv = *(const short8*)(WT2 + (size_t)(cg2 * 16 + l15) * 128 + ka);
      a2 = __builtin_amdgcn_mfma_f32_16x16x32_bf16(af, bvv, a2, 0, 0, 0);
      auto red2 = reinterpret_cast<float(*)[16][20]>(&als[0][0][0]);
      if (kh2 > 0){
        int slot = (kh2 - 1) * 4 + cg2;
#pragma unroll
        for (int r = 0; r < 4; ++r)
          red2[slot][quad * 4 + r][l15] = a2[r];
      }
      __syncthreads();
      if (kh2 == 0){
#pragma unroll
        for (int s = 0; s < 3; ++s)
#pragma unroll
          for (int r = 0; r < 4; ++r)
            a2[r] += red2[s * 4 + cg2][quad * 4 + r][l15];
        int c2 = cg2 * 16 + l15;
#pragma unroll
        for (int r = 0; r < 4; ++r){
          int n = rb + quad * 4 + r;
          if (n < N) hx[(size_t)n * 64 + c2] = f2b(a2[r] * dinvp[n]);
        }
      }
    }
  }
}

extern "C" void kernel_launch(void* const* d_in, const int* in_sizes, int n_in,
                              void* d_out, int out_size, void* d_ws, size_t ws_size,
                              hipStream_t stream)
{
  const void* x_in   = d_in[0];
  const int*  ei     = (const int*)d_in[1];
  const void *nn1_w1 = d_in[2], *nn1_b1 = d_in[3], *nn1_w2 = d_in[4], *nn1_b2 = d_in[5];
  const void *nn1_w3 = d_in[6], *nn1_b3 = d_in[7];
  const void *bn0_g = d_in[8],  *bn0_b = d_in[9],  *bn0_m = d_in[10], *bn0_v = d_in[11];
  const void *bn1_g = d_in[12], *bn1_b = d_in[13], *bn1_m = d_in[14], *bn1_v = d_in[15];
  const void *bn2_g = d_in[16], *bn2_b = d_in[17], *bn2_m = d_in[18], *bn2_v = d_in[19];
  const void *gcn1_w = d_in[20], *gcn1_b = d_in[21];
  const void *gat1_w = d_in[22], *gat1_as = d_in[23], *gat1_ad = d_in[24], *gat1_b = d_in[25];
  const void *gcn2_w = d_in[26], *gcn2_b = d_in[27];
  const void *gat2_w = d_in[28], *gat2_as = d_in[29], *gat2_ad = d_in[30], *gat2_b = d_in[31];
  const void *mlp_w1 = d_in[32], *mlp_b1 = d_in[33], *mlp_w2 = d_in[34], *mlp_b2 = d_in[35];
  const void *mlp_w3 = d_in[36], *mlp_b3 = d_in[37], *mlp_w4 = d_in[38], *mlp_b4 = d_in[39];
  (void)n_in;

  const int N  = in_sizes[0] / 64;
  const int E  = in_sizes[1] / 2;
  const int Ep = E + N;
  const int TB = 256;

  if ((long long)out_size != (long long)N * 193 || N > 65535){
    k_stampfill<<<(int)cdivll(out_size, TB), TB, 0, stream>>>((bf16*)d_out, out_size, 8192.f);
    return;
  }
  size_t need = 2900ull * (size_t)N + 500000ull;
  if (ws_size < need){
    k_stampfill<<<(int)cdivll(out_size, TB), TB, 0, stream>>>((bf16*)d_out, out_size, 1024.f);
    return;
  }

  // ws layout: flags | X | A | B | DINV | ASD | rowptr | colu(u16) | HX(bf16) | WTA(bf16)
  char* wsb = (char*)d_ws;
  int*   FLAGS = (int*)wsb;
  float* X    = (float*)(wsb + 16);
  float* A    = X + (size_t)N * 128;
  float* B    = A + (size_t)N * 128;
  float* DINV = B + (size_t)N * 128;
  float* AS   = DINV + N;                       // [N][10] f32: a_src(5) | a_dst(5)
  int*   ROWP = (int*)(AS + (size_t)N * 2 * HEADS);
  unsigned short* COLU = (unsigned short*)(ROWP + N + 1);
  bf16*  HX   = (bf16*)(COLU + ((Ep + 7) & ~7)); // gcn projections [N,128]/[N,64] bf16
  bf16*  WTA  = (bf16*)(((uintptr_t)(HX + (size_t)N * 640) + 15) & ~(uintptr_t)15);
  bf16*  BB   = (bf16*)A;    // bf16 GCN output (gat input), aliases A
  int* CNT = (int*)AS;
  int* CUR = CNT + N;
  const int ATT1_OFF = 186368;   // [64][128] folded att weights (gat1)
  const int ATT2_OFF = 194560;   // [64][64]  folded att weights (gat2)

  k_detect<<<1, 256, 0, stream>>>((const unsigned short*)x_in, ei, FLAGS);

  // ---- pack all weights + zero CNT/CUR + fold att weights (one dispatch) ----
  PackArgs P;
  P.d[0] = {nn1_w1,  64, 64, 128, 128, 0, 0};
  P.d[1] = {nn1_w2, 128,128,  64,  64, 8192, 0};
  P.d[2] = {nn1_w3,  64, 64, 128, 128, 16384, 0};
  P.d[3] = {gcn1_w, 128,128, 128, 128, 24576, 0};
  P.d[4] = {gat1_w, 128,640, 128, 128, 40960, 5};   // head-folded: [c][h*128+k]
  P.d[5] = {gcn2_w, 128,128,  64,  64, 122880, 0};
  P.d[6] = {gat2_w,  64,320,  64,  64, 131072, 5};  // head-folded: [c][h*64+k]
  P.d[7] = {mlp_w1, 192,192,  96, 128, 151552, 0};
  P.d[8] = {mlp_w2,  96, 96,  48,  64, 176128, 0};
  P.d[9] = {mlp_w3,  48, 64,  24,  64, 182272, 0};
  P.total = 186368;
  k_packall<<<(int)cdivll(P.total + 2 * N + 12288, TB), TB, 0, stream>>>(
      P, WTA, CNT, 2 * N, gat1_w, gat1_as, gat1_ad, gat2_w, gat2_as, gat2_ad, FLAGS);

  // ---- CSR build (dinv fused into scatter) ----
  k_hist<<<(int)cdivll(Ep, TB), TB, 0, stream>>>(ei, E, N, CNT, FLAGS);
  k_scan<<<1, 1024, 0, stream>>>(CNT, ROWP, N);
  k_scatter<<<(int)cdivll(Ep, TB), TB, 0, stream>>>(ei, E, N, ROWP, CUR, COLU, DINV, FLAGS);

  int rowsg = (int)cdivll(N, 4);
  int rows16 = (int)cdivll(N, 16);

  // ---- stage A: fused nn1 MLP (+bn0+leaky) -> X f32, + gcn1 projection (×dinv) -> HX ----
  k_nn1f<<<rows16, 256, 0, stream>>>(x_in, WTA, nn1_b1, nn1_b2, nn1_b3,
                                     bn0_g, bn0_b, bn0_m, bn0_v, DINV, X, HX, N, FLAGS);

  // ---- GCN1 aggregate (+att1 logit dots) — HX pre-scaled, no per-edge dinv ----
  k_gcn_csr<<<rowsg, 256, 0, stream>>>(ROWP, COLU, HX, DINV, gcn1_b, BB, N, 128,
                                       WTA + ATT1_OFF, AS, FLAGS);

  // ---- GAT1: softmax+gather+project+bn1+skip -> d_out[:,0:128], + gcn2 proj (×dinv) -> HX
  k_gat_proj<128><<<rows16, 1024, 0, stream>>>(ROWP, COLU, BB, AS, WTA + 40960, gat1_b,
      bn1_g, bn1_b, bn1_m, bn1_v, X, d_out, 0, WTA + 122880, HX, DINV, N, FLAGS);

  // ---- GCN2 aggregate (+att2 dots) — HX pre-scaled ----
  k_gcn_csr<<<rowsg, 256, 0, stream>>>(ROWP, COLU, HX, DINV, gcn2_b, BB, N, 64,
                                       WTA + ATT2_OFF, AS, FLAGS);

  // ---- GAT2: softmax+gather+project+bn2 -> d_out[:,128:192] ----
  k_gat_proj<64><<<rows16, 1024, 0, stream>>>(ROWP, COLU, BB, AS, WTA + 131072, gat2_b,
      bn2_g, bn2_b, bn2_m, bn2_v, nullptr, d_out, 128, nullptr, nullptr, nullptr, N, FLAGS);

  // ---- fused node_pred MLP: d_out[N,192] -> probs at d_out[N*192..] ----
  k_mlpf<<<rows16, 256, 0, stream>>>(d_out, WTA, mlp_b1, mlp_b2, mlp_b3,
                                     mlp_w4, mlp_b4, d_out, N, FLAGS);
}